// Round 12
// baseline (4642.390 us; speedup 1.0000x reference)
//
#include <hip/hip_runtime.h>
#include <hip/hip_bf16.h>
#include <hip/hip_cooperative_groups.h>

namespace cg = cooperative_groups;

using s16x8 = __attribute__((ext_vector_type(8))) short;   // 8 bf16 (4 VGPRs) MFMA frag
using f32x4 = __attribute__((ext_vector_type(4))) float;   // MFMA accumulator

constexpr int BB = 64;    // batch
constexpr int SS = 512;   // seq len
constexpr int II = 1024;  // input dim
constexpr int HH = 1024;  // hidden dim

__device__ __forceinline__ unsigned short f2bf(float f) {
  unsigned u = __float_as_uint(f);
  unsigned r = u + 0x7fffu + ((u >> 16) & 1u);   // RN-even
  return (unsigned short)(r >> 16);
}
__device__ __forceinline__ float bf2f(unsigned short h) {
  return __uint_as_float(((unsigned)h) << 16);
}

// ---------------------------------------------------------------------------
// Single bf16 W in MFMA-linear fragment order (16 MB):
// Wpk[blk 256][ks 2][kb 32][lane 64][e 8]; lane: n=lane&15 (gate-row), u=lane>>4;
// element k (within ks-part) = kb*32 + u*8 + e.
// ---------------------------------------------------------------------------
__global__ void __launch_bounds__(256) pack_w_single(
    const float* __restrict__ wii, const float* __restrict__ whi_,
    const float* __restrict__ wif, const float* __restrict__ whf,
    const float* __restrict__ wig, const float* __restrict__ whg,
    const float* __restrict__ wio, const float* __restrict__ who,
    unsigned short* __restrict__ Wpk)
{
  unsigned f = blockIdx.x * 256 + threadIdx.x;   // frag id, 0..1048575
  int lane = f & 63;
  int kb   = (f >> 6) & 31;
  int ks   = (f >> 11) & 1;
  int blk  = (int)(f >> 12);
  int n = lane & 15, u = lane >> 4;
  int hc = blk * 4 + (n >> 2), g = n & 3;
  int k  = kb * 32 + u * 8;
  const float* wi4[4] = {wii, wif, wig, wio};
  const float* wh4[4] = {whi_, whf, whg, who};
  const float* src = (ks == 0) ? (wi4[g] + (size_t)hc * 1024 + k)
                               : (wh4[g] + (size_t)hc * 1024 + k);
  float4 v0 = *(const float4*)src;
  float4 v1 = *(const float4*)(src + 4);
  s16x8 r;
  r[0] = (short)f2bf(v0.x); r[1] = (short)f2bf(v0.y);
  r[2] = (short)f2bf(v0.z); r[3] = (short)f2bf(v0.w);
  r[4] = (short)f2bf(v1.x); r[5] = (short)f2bf(v1.y);
  r[6] = (short)f2bf(v1.z); r[7] = (short)f2bf(v1.w);
  *(s16x8*)(Wpk + (size_t)f * 8) = r;
}

__global__ void __launch_bounds__(256) pack_bias(
    const float* __restrict__ bii, const float* __restrict__ bhi,
    const float* __restrict__ bif, const float* __restrict__ bhf,
    const float* __restrict__ big, const float* __restrict__ bhg,
    const float* __restrict__ bio, const float* __restrict__ bho,
    float* __restrict__ biasC)
{
  int cidx = blockIdx.x * 256 + threadIdx.x;  // 0..4095
  int col = cidx & 15, blk = cidx >> 4;
  int hc = blk * 4 + (col >> 2), g = col & 3;
  const float* bi4[4] = {bii, bif, big, bio};
  const float* bh4[4] = {bhi, bhf, bhg, bho};
  biasC[cidx] = bi4[g][hc] + bh4[g][hc];
}

// x [B][S][I] fp32 -> xb [S][B][I] bf16
__global__ void __launch_bounds__(256) conv_x(const float* __restrict__ x,
                                              unsigned short* __restrict__ xb)
{
  int bs = blockIdx.x;
  int b = bs >> 9, s = bs & 511;
  float4 v = *(const float4*)(x + ((size_t)b * 512 + s) * 1024 + threadIdx.x * 4);
  *(ushort4*)(xb + ((size_t)s * 64 + b) * 1024 + threadIdx.x * 4) =
      make_ushort4(f2bf(v.x), f2bf(v.y), f2bf(v.z), f2bf(v.w));
}

// hseq [S+1][B][H] bf16 -> out hidden_seq [B][S][H] fp32
__global__ void __launch_bounds__(256) conv_out(const unsigned short* __restrict__ hseq,
                                                float* __restrict__ out)
{
  int bt = blockIdx.x;             // 0..32767
  int b = bt >> 9, t = bt & 511;
  ushort4 v = *(const ushort4*)(hseq + (size_t)(t + 1) * 65536 + b * 1024 + threadIdx.x * 4);
  float4 o;
  o.x = bf2f(v.x); o.y = bf2f(v.y); o.z = bf2f(v.z); o.w = bf2f(v.w);
  *(float4*)(out + ((size_t)b * 512 + t) * 1024 + threadIdx.x * 4) = o;
}

// ---------------------------------------------------------------------------
// Hierarchical monotone barrier (r4; probe-measured inside 2.45us skeleton).
// ---------------------------------------------------------------------------
__device__ __forceinline__ void hbar_arrive(int* cnt, int blk, int kbar) {
  int g = blk & 7;
  int* lp = cnt + g * 16;
  __hip_atomic_fetch_add(lp, 1, __ATOMIC_RELAXED, __HIP_MEMORY_SCOPE_AGENT);
  if (blk < 8) {   // master of group g == blk
    while (__hip_atomic_load(lp, __ATOMIC_RELAXED, __HIP_MEMORY_SCOPE_AGENT) < 32 * kbar)
      __builtin_amdgcn_s_sleep(1);
    __hip_atomic_fetch_add(cnt + 8 * 16, 1, __ATOMIC_RELAXED, __HIP_MEMORY_SCOPE_AGENT);
  }
}
__device__ __forceinline__ void hbar_spin(int* cnt, int kbar) {
  int* gp = cnt + 8 * 16;
  while (__hip_atomic_load(gp, __ATOMIC_RELAXED, __HIP_MEMORY_SCOPE_AGENT) < 8 * kbar)
    __builtin_amdgcn_s_sleep(1);
}

// direct-load K-half GEMM (prologue only)
__device__ __forceinline__ void gemm_half1(const unsigned short* __restrict__ aptr,
                                           const s16x8* __restrict__ WlV, int wb,
                                           f32x4& out) {
  s16x8 a[16];
#pragma unroll
  for (int kb = 0; kb < 16; ++kb) a[kb] = *(const s16x8*)(aptr + kb * 32);
  f32x4 c0_ = {0.f, 0.f, 0.f, 0.f}, c1_ = c0_;
#pragma unroll
  for (int kb = 0; kb < 16; kb += 2) {
    c0_ = __builtin_amdgcn_mfma_f32_16x16x32_bf16(a[kb],     WlV[wb + kb * 64],       c0_, 0, 0, 0);
    c1_ = __builtin_amdgcn_mfma_f32_16x16x32_bf16(a[kb + 1], WlV[wb + (kb + 1) * 64], c1_, 0, 0, 0);
  }
  out = c0_ + c1_;
}

// ---------------------------------------------------------------------------
// Async-staged K-half GEMM: 16 global_load_lds (async DMA, zero VGPR cost,
// deep queue) in 2 rounds of 8 through a 8KB/wave LDS slot. Round-1 RTT
// overlaps round-0 MFMAs. hipcc cannot sink the DMA intrinsics (r4/r5/r10's
// register-allocator defeat doesn't apply). Per-lane SOURCE addr is legal
// (m97/m173); LDS dest is wave-uniform + lane*16, matching frag-linear
// read-back exactly (conflict-free ds_read_b128).
// ---------------------------------------------------------------------------
__device__ __forceinline__ f32x4 gemm_staged(const unsigned short* gp,
                                             s16x8* sw, int lane,
                                             const s16x8* __restrict__ WlV, int wb)
{
  // round 0 issue: chunks 0..7 -> slots 0..7
#pragma unroll
  for (int j = 0; j < 8; ++j)
    __builtin_amdgcn_global_load_lds(
        (const __attribute__((address_space(1))) void*)(gp + j * 32),
        (__attribute__((address_space(3))) void*)(sw + j * 64), 16, 0, 0);
  asm volatile("s_waitcnt vmcnt(0)" ::: "memory");
  __builtin_amdgcn_sched_barrier(0);
  s16x8 a[8];
#pragma unroll
  for (int j = 0; j < 8; ++j) a[j] = sw[j * 64 + lane];
  asm volatile("s_waitcnt lgkmcnt(0)" ::: "memory");
  __builtin_amdgcn_sched_barrier(0);
  // round 1 issue: chunks 8..15 -> slots 0..7 (RTT hides under round-0 MFMAs)
#pragma unroll
  for (int j = 8; j < 16; ++j)
    __builtin_amdgcn_global_load_lds(
        (const __attribute__((address_space(1))) void*)(gp + j * 32),
        (__attribute__((address_space(3))) void*)(sw + (j - 8) * 64), 16, 0, 0);
  f32x4 c0_ = {0.f, 0.f, 0.f, 0.f}, c1_ = c0_;
#pragma unroll
  for (int j = 0; j < 8; j += 2) {
    c0_ = __builtin_amdgcn_mfma_f32_16x16x32_bf16(a[j],     WlV[wb + j * 64],       c0_, 0, 0, 0);
    c1_ = __builtin_amdgcn_mfma_f32_16x16x32_bf16(a[j + 1], WlV[wb + (j + 1) * 64], c1_, 0, 0, 0);
  }
  asm volatile("s_waitcnt vmcnt(0)" ::: "memory");
  __builtin_amdgcn_sched_barrier(0);
#pragma unroll
  for (int j = 0; j < 8; ++j) a[j] = sw[j * 64 + lane];
#pragma unroll
  for (int j = 0; j < 8; j += 2) {
    c0_ = __builtin_amdgcn_mfma_f32_16x16x32_bf16(a[j],     WlV[wb + (8 + j) * 64],     c0_, 0, 0, 0);
    c1_ = __builtin_amdgcn_mfma_f32_16x16x32_bf16(a[j + 1], WlV[wb + (9 + j) * 64],     c1_, 0, 0, 0);
  }
  return c0_ + c1_;
}

// ---------------------------------------------------------------------------
// Persistent LSTM v11 = r11 structure + async-staged GEMM loads.
// 256 blocks x 512 threads, 1 block/CU.
// Wave w: m = w&3 (batch 16-row tile), kh = w>>2 (K-half 512).
// A: publish xacc(t); STAGED h-GEMM(t); publish h partials.          -> S1
// B: gate math sums 4 partials + bias.                               -> S2
// C: flush h_{t+1} (64 x 8B agent stores).                           -> S3
// D: arrive; STAGED x-GEMM(t+1) under the wait; spin.                -> S4
// ---------------------------------------------------------------------------
__global__ void __launch_bounds__(512, 1) lstm_fast10(
    const unsigned short* __restrict__ Wpk,  // [256][2][32][64][8] bf16 (16 MB)
    const float* __restrict__ biasC,         // [256][16]
    const unsigned short* __restrict__ xb,   // [S][B][I] bf16
    unsigned short* __restrict__ hseq,       // [S+1][B][H] bf16 rotating
    int* __restrict__ cnt,                   // 9 lines x 64B, monotone
    const float* __restrict__ h0,
    const float* __restrict__ c0,
    float* __restrict__ out)                 // [hidden_seq][h_f][c_f]
{
  __shared__ s16x8 WlV[4096];                // 64 KB single-W frags
  __shared__ s16x8 stageV[4096];             // 64 KB async-stage buffer (8KB/wave)
  __shared__ float gX[2][64][17];            // x partials per K-half
  __shared__ float gH[2][64][17];            // h partials per K-half
  __shared__ float biasLds[16];
  __shared__ short hOutLds[64][4];           // staged h_{t+1} for 8B flush

  const int tid  = threadIdx.x;
  const int blk  = blockIdx.x;
  const int wave = tid >> 6, lane = tid & 63;
  const int m  = wave & 3;        // batch tile
  const int kh = wave >> 2;       // K-half within each operand
  const int arow = m * 16 + (lane & 15);
  const int koff = (lane >> 4) * 8;
  const int aoff = arow * 1024 + kh * 512 + koff;   // element offset in a t-slot
  const int wxb = (kh * 16) * 64 + lane;            // x-part W frag base in LDS
  const int whb = (32 + kh * 16) * 64 + lane;       // h-part W frag base in LDS
  const int drow = m * 16 + (lane >> 4) * 4;
  const int dcol = lane & 15;
  s16x8* sw = stageV + wave * 512;                  // this wave's 8KB stage slot

  // stage this block's W chunk (64 KB linear; frag order == read order)
  {
    const s16x8* src = (const s16x8*)(Wpk + (size_t)blk * 32768);
#pragma unroll
    for (int it = 0; it < 8; ++it) WlV[it * 512 + tid] = src[it * 512 + tid];
  }
  if (tid < 16) biasLds[tid] = biasC[blk * 16 + tid];

  // init hseq slot 0 from h0 with agent-visible stores
  if (tid < 128) {
    int p = blk * 128 + tid;                 // pair index over B*H/2
    unsigned lo = f2bf(h0[2 * p]), hi = f2bf(h0[2 * p + 1]);
    __hip_atomic_store((unsigned*)(hseq + 2 * p), lo | (hi << 16),
                       __ATOMIC_RELAXED, __HIP_MEMORY_SCOPE_AGENT);
  }
  const int rb_batch = tid >> 2, rb_j = tid & 3;
  float c_reg = 0.f;
  if (tid < 256) c_reg = c0[rb_batch * 1024 + blk * 4 + rb_j];

  __syncthreads();                           // W staged; h0 stores drained

  // prologue: x-GEMM(0), direct loads (once)
  f32x4 xacc;
  gemm_half1(xb + aoff, WlV, wxb, xacc);

  if (tid == 256) { hbar_arrive(cnt, blk, 1); hbar_spin(cnt, 1); }
  __syncthreads();                           // hseq slot 0 globally visible

  for (int t = 0; t < SS; ++t) {
    // ---- phase A: publish xacc(t); STAGED h-GEMM(t); publish h partials ----
#pragma unroll
    for (int r = 0; r < 4; ++r) gX[kh][drow + r][dcol] = xacc[r];
    {
      f32x4 hs = gemm_staged(hseq + (size_t)t * 65536 + aoff, sw, lane, WlV, whb);
#pragma unroll
      for (int r = 0; r < 4; ++r) gH[kh][drow + r][dcol] = hs[r];
    }
    __syncthreads();                         // S1

    // ---- phase B: gate math over 4 partials ----
    if (tid < 256) {
      int c0i = rb_j * 4;
      float si = gX[0][rb_batch][c0i + 0] + gX[1][rb_batch][c0i + 0]
               + gH[0][rb_batch][c0i + 0] + gH[1][rb_batch][c0i + 0] + biasLds[c0i + 0];
      float sf = gX[0][rb_batch][c0i + 1] + gX[1][rb_batch][c0i + 1]
               + gH[0][rb_batch][c0i + 1] + gH[1][rb_batch][c0i + 1] + biasLds[c0i + 1];
      float sg = gX[0][rb_batch][c0i + 2] + gX[1][rb_batch][c0i + 2]
               + gH[0][rb_batch][c0i + 2] + gH[1][rb_batch][c0i + 2] + biasLds[c0i + 2];
      float so = gX[0][rb_batch][c0i + 3] + gX[1][rb_batch][c0i + 3]
               + gH[0][rb_batch][c0i + 3] + gH[1][rb_batch][c0i + 3] + biasLds[c0i + 3];
      float iv = 1.f / (1.f + __expf(-si));
      float fv = 1.f / (1.f + __expf(-sf));
      float gv = tanhf(sg);
      float ov = 1.f / (1.f + __expf(-so));
      c_reg = fv * c_reg + iv * gv;
      float hv = ov * tanhf(c_reg);
      hOutLds[rb_batch][rb_j] = (short)f2bf(hv);
      if (t == SS - 1) {
        int hcg = blk * 4 + rb_j;
        out[(size_t)BB * SS * HH + rb_batch * 1024 + hcg] = hv;            // h_f fp32
        out[(size_t)BB * SS * HH + 65536 + rb_batch * 1024 + hcg] = c_reg; // c_f fp32
      }
    }
    __syncthreads();                         // S2

    // ---- phase C: flush h_{t+1} (64 x 8B agent stores) ----
    if (tid < 64) {
      unsigned long long v = *(const unsigned long long*)&hOutLds[tid][0];
      __hip_atomic_store(
          (unsigned long long*)(hseq + (size_t)(t + 1) * 65536 + tid * 1024 + blk * 4),
          v, __ATOMIC_RELAXED, __HIP_MEMORY_SCOPE_AGENT);
    }
    __syncthreads();                         // S3: flush drained per thread

    // ---- phase D: arrive; STAGED x-GEMM(t+1) under the wait; spin ----
    if (t + 1 < SS) {
      if (tid == 256) hbar_arrive(cnt, blk, t + 2);
      xacc = gemm_staged(xb + (size_t)(t + 1) * 65536 + aoff, sw, lane, WlV, wxb);
      if (tid == 256) hbar_spin(cnt, t + 2);
      __syncthreads();                       // S4: h_{t+1} globally visible
    }
  }
}

// ---------------------------------------------------------------------------
// LEGACY fallback (cg::grid.sync) for small ws_size. Unchanged.
// ---------------------------------------------------------------------------
__global__ void __launch_bounds__(256) pack_w(
    const float* __restrict__ wii, const float* __restrict__ whi_,
    const float* __restrict__ wif, const float* __restrict__ whf,
    const float* __restrict__ wig, const float* __restrict__ whg,
    const float* __restrict__ wio, const float* __restrict__ who,
    unsigned short* __restrict__ Whi, unsigned short* __restrict__ Wlo)
{
  size_t idx = ((size_t)blockIdx.x * 256 + threadIdx.x) * 4;
  int k   = (int)(idx & 2047);
  int rg  = (int)(idx >> 11);
  int row = rg & 15;
  int blk = rg >> 4;
  int hc  = blk * 4 + (row >> 2);
  int g   = row & 3;
  const float* wi4[4] = {wii, wif, wig, wio};
  const float* wh4[4] = {whi_, whf, whg, who};
  const float* src = (k < 1024) ? (wi4[g] + (size_t)hc * 1024 + k)
                                : (wh4[g] + (size_t)hc * 1024 + (k - 1024));
  float4 v = *(const float4*)src;
  float vv[4] = {v.x, v.y, v.z, v.w};
  unsigned short h_[4], l_[4];
#pragma unroll
  for (int j = 0; j < 4; ++j) {
    unsigned short h = f2bf(vv[j]);
    h_[j] = h;
    l_[j] = f2bf(vv[j] - bf2f(h));
  }
  *(ushort4*)(Whi + idx) = make_ushort4(h_[0], h_[1], h_[2], h_[3]);
  *(ushort4*)(Wlo + idx) = make_ushort4(l_[0], l_[1], l_[2], l_[3]);
}

__global__ void __launch_bounds__(512, 1) lstm_seq_legacy(
    const unsigned short* __restrict__ W,
    const float* __restrict__ biasC,
    const float* __restrict__ xin,
    unsigned short* __restrict__ hb,
    const float* __restrict__ h0,
    const float* __restrict__ c0,
    float* __restrict__ out)
{
  __shared__ short Wl[2][16][2048];
  __shared__ float gLds[2][64][17];
  __shared__ float biasLds[16];

  const int tid  = threadIdx.x;
  const int blk  = blockIdx.x;
  const int wave = tid >> 6;
  const int lane = tid & 63;
  const int m    = wave >> 1;
  const int ks   = wave & 1;
  const int arow = m * 16 + (lane & 15);
  const int koff = (lane >> 4) * 8;
  const int brow = lane & 15;
  const int bswz = (brow & 7) << 4;

  {
    const char* srcH = (const char*)W + (size_t)blk * 65536;
    const char* srcL = (const char*)W + 16777216u + (size_t)blk * 65536;
    char* dstH = (char*)&Wl[0][0][0];
    char* dstL = (char*)&Wl[1][0][0];
#pragma unroll
    for (int it = 0; it < 8; ++it) {
      int boff = it * 8192 + tid * 16;
      int row  = boff >> 12;
      int colb = boff & 4095;
      int dsw  = row * 4096 + (colb ^ ((row & 7) << 4));
      *(int4*)(dstH + dsw) = *(const int4*)(srcH + boff);
      *(int4*)(dstL + dsw) = *(const int4*)(srcL + boff);
    }
  }
  if (tid < 16) biasLds[tid] = biasC[blk * 16 + tid];
  if (tid < 256) {
    int e = blk * 256 + tid;
    hb[e] = f2bf(h0[e]);
  }
  const int rb_batch = tid >> 2, rb_j = tid & 3;
  float c_reg = 0.f;
  if (tid < 256) c_reg = c0[rb_batch * 1024 + blk * 4 + rb_j];

  cg::grid_group grid = cg::this_grid();
  __syncthreads();
  grid.sync();

  const char* wrow = (const char*)&Wl[0][0][0] + brow * 4096;
  const int kbyte = ks * 2048;

  for (int t = 0; t < SS; ++t) {
    const unsigned short* hcur = hb + (t & 1) * 65536;
    f32x4 accH = {0.f, 0.f, 0.f, 0.f};
    f32x4 accL = {0.f, 0.f, 0.f, 0.f};

    if (ks == 1) {
      const unsigned short* aptr = hcur + arow * 1024 + koff;
#pragma unroll
      for (int kk = 0; kk < 1024; kk += 32) {
        s16x8 a = *(const s16x8*)(aptr + kk);
        int cb = (kbyte + (kk + koff) * 2) ^ bswz;
        s16x8 bh = *(const s16x8*)(wrow + cb);
        s16x8 bl = *(const s16x8*)(wrow + 65536 + cb);
        accH = __builtin_amdgcn_mfma_f32_16x16x32_bf16(a, bh, accH, 0, 0, 0);
        accL = __builtin_amdgcn_mfma_f32_16x16x32_bf16(a, bl, accL, 0, 0, 0);
      }
    } else {
      const float* xp = xin + ((size_t)arow * 512 + t) * 1024 + koff;
#pragma unroll
      for (int kk = 0; kk < 1024; kk += 32) {
        float4 f0 = *(const float4*)(xp + kk);
        float4 f1 = *(const float4*)(xp + kk + 4);
        s16x8 a;
        a[0] = (short)f2bf(f0.x); a[1] = (short)f2bf(f0.y);
        a[2] = (short)f2bf(f0.z); a[3] = (short)f2bf(f0.w);
        a[4] = (short)f2bf(f1.x); a[5] = (short)f2bf(f1.y);
        a[6] = (short)f2bf(f1.z); a[7] = (short)f2bf(f1.w);
        int cb = ((kk + koff) * 2) ^ bswz;
        s16x8 bh = *(const s16x8*)(wrow + cb);
        s16x8 bl = *(const s16x8*)(wrow + 65536 + cb);
        accH = __builtin_amdgcn_mfma_f32_16x16x32_bf16(a, bh, accH, 0, 0, 0);
        accL = __builtin_amdgcn_mfma_f32_16x16x32_bf16(a, bl, accL, 0, 0, 0);
      }
    }

    {
      f32x4 acc = accH + accL;
      int drow = m * 16 + (lane >> 4) * 4;
      int dcol = lane & 15;
#pragma unroll
      for (int r = 0; r < 4; ++r) gLds[ks][drow + r][dcol] = acc[r];
    }
    __syncthreads();

    if (tid < 256) {
      int c0i = rb_j * 4;
      float si = gLds[0][rb_batch][c0i + 0] + gLds[1][rb_batch][c0i + 0] + biasLds[c0i + 0];
      float sf = gLds[0][rb_batch][c0i + 1] + gLds[1][rb_batch][c0i + 1] + biasLds[c0i + 1];
      float sg = gLds[0][rb_batch][c0i + 2] + gLds[1][rb_batch][c0i + 2] + biasLds[c0i + 2];
      float so = gLds[0][rb_batch][c0i + 3] + gLds[1][rb_batch][c0i + 3] + biasLds[c0i + 3];
      float iv = 1.f / (1.f + __expf(-si));
      float fv = 1.f / (1.f + __expf(-sf));
      float gv = tanhf(sg);
      float ov = 1.f / (1.f + __expf(-so));
      c_reg = fv * c_reg + iv * gv;
      float hv = ov * tanhf(c_reg);
      int hcg = blk * 4 + rb_j;
      out[(size_t)rb_batch * (SS * HH) + (size_t)t * HH + hcg] = hv;
      hb[((t + 1) & 1) * 65536 + rb_batch * 1024 + hcg] = f2bf(hv);
      if (t == SS - 1) {
        out[(size_t)BB * SS * HH + rb_batch * 1024 + hcg] = hv;
        out[(size_t)BB * SS * HH + 65536 + rb_batch * 1024 + hcg] = c_reg;
      }
    }
    grid.sync();
  }
}

extern "C" void kernel_launch(void* const* d_in, const int* in_sizes, int n_in,
                              void* d_out, int out_size, void* d_ws, size_t ws_size,
                              hipStream_t stream) {
  const float* xin = (const float*)d_in[0];
  const float* h0  = (const float*)d_in[1];
  const float* c0  = (const float*)d_in[2];
  const float* wii = (const float*)d_in[3];
  const float* whi = (const float*)d_in[4];
  const float* bii = (const float*)d_in[5];
  const float* bhi = (const float*)d_in[6];
  const float* wif = (const float*)d_in[7];
  const float* whf = (const float*)d_in[8];
  const float* bif = (const float*)d_in[9];
  const float* bhf = (const float*)d_in[10];
  const float* wig = (const float*)d_in[11];
  const float* whg = (const float*)d_in[12];
  const float* big = (const float*)d_in[13];
  const float* bhg = (const float*)d_in[14];
  const float* wio = (const float*)d_in[15];
  const float* who = (const float*)d_in[16];
  const float* bio = (const float*)d_in[17];
  const float* bho = (const float*)d_in[18];
  float* out = (float*)d_out;

  char* ws = (char*)d_ws;
  // fast layout (same offsets as r2-r11; Wpk uses 16 MB of its 32 MB slot)
  unsigned short* Wpk   = (unsigned short*)ws;                 // 16 MB
  float*          biasC = (float*)(ws + 33554432);             // 16 KB
  int*            cnt   = (int*)(ws + 33570816);               // 64 KB slot (uses 576 B)
  unsigned short* hseq  = (unsigned short*)(ws + 33636352);    // 513*131072
  unsigned short* xb    = (unsigned short*)(ws + 100876288);   // 64 MB
  const size_t need_fast_xb = 100876288ull + 67108864ull;      // 167985152

  // legacy layout
  unsigned short* Wl_  = (unsigned short*)ws;                  // 32 MB hi+lo
  unsigned short* hb   = (unsigned short*)(ws + 33570816);     // 256 KB

  if (ws_size >= need_fast_xb) {
    pack_w_single<<<4096, 256, 0, stream>>>(wii, whi, wif, whf, wig, whg, wio, who, Wpk);
    pack_bias<<<16, 256, 0, stream>>>(bii, bhi, bif, bhf, big, bhg, bio, bho, biasC);
    conv_x<<<32768, 256, 0, stream>>>(xin, xb);
    hipMemsetAsync(cnt, 0, 4096, stream);

    void* ka[] = {(void*)&Wpk, (void*)&biasC, (void*)&xb,
                  (void*)&hseq, (void*)&cnt, (void*)&h0, (void*)&c0, (void*)&out};
    hipLaunchCooperativeKernel(reinterpret_cast<const void*>(&lstm_fast10),
                               dim3(256), dim3(512), ka, 0, stream);
    conv_out<<<32768, 256, 0, stream>>>(hseq, out);
  } else {
    pack_w<<<8192, 256, 0, stream>>>(wii, whi, wif, whf, wig, whg, wio, who,
                                     Wl_, Wl_ + 8388608);
    pack_bias<<<16, 256, 0, stream>>>(bii, bhi, bif, bhf, big, bhg, bio, bho, biasC);
    void* ka[] = {(void*)&Wl_, (void*)&biasC, (void*)&xin,
                  (void*)&hb, (void*)&h0, (void*)&c0, (void*)&out};
    hipLaunchCooperativeKernel(reinterpret_cast<const void*>(&lstm_seq_legacy),
                               dim3(256), dim3(512), ka, 0, stream);
  }
}

// Round 13
// 4441.761 us; speedup vs baseline: 1.0452x; 1.0452x over previous
//
#include <hip/hip_runtime.h>
#include <hip/hip_bf16.h>
#include <hip/hip_cooperative_groups.h>

namespace cg = cooperative_groups;

using s16x8 = __attribute__((ext_vector_type(8))) short;   // 8 bf16 (4 VGPRs) MFMA frag
using f32x4 = __attribute__((ext_vector_type(4))) float;   // MFMA accumulator

constexpr int BB = 64;    // batch
constexpr int SS = 512;   // seq len
constexpr int II = 1024;  // input dim
constexpr int HH = 1024;  // hidden dim

__device__ __forceinline__ unsigned short f2bf(float f) {
  unsigned u = __float_as_uint(f);
  unsigned r = u + 0x7fffu + ((u >> 16) & 1u);   // RN-even
  return (unsigned short)(r >> 16);
}
__device__ __forceinline__ float bf2f(unsigned short h) {
  return __uint_as_float(((unsigned)h) << 16);
}

// ---------------------------------------------------------------------------
// Single bf16 W in MFMA-linear fragment order (16 MB):
// Wpk[blk 256][ks 2][kb 32][lane 64][e 8]; lane: n=lane&15 (gate-row), u=lane>>4;
// element k (within ks-part) = kb*32 + u*8 + e.
// ---------------------------------------------------------------------------
__global__ void __launch_bounds__(256) pack_w_single(
    const float* __restrict__ wii, const float* __restrict__ whi_,
    const float* __restrict__ wif, const float* __restrict__ whf,
    const float* __restrict__ wig, const float* __restrict__ whg,
    const float* __restrict__ wio, const float* __restrict__ who,
    unsigned short* __restrict__ Wpk)
{
  unsigned f = blockIdx.x * 256 + threadIdx.x;   // frag id, 0..1048575
  int lane = f & 63;
  int kb   = (f >> 6) & 31;
  int ks   = (f >> 11) & 1;
  int blk  = (int)(f >> 12);
  int n = lane & 15, u = lane >> 4;
  int hc = blk * 4 + (n >> 2), g = n & 3;
  int k  = kb * 32 + u * 8;
  const float* wi4[4] = {wii, wif, wig, wio};
  const float* wh4[4] = {whi_, whf, whg, who};
  const float* src = (ks == 0) ? (wi4[g] + (size_t)hc * 1024 + k)
                               : (wh4[g] + (size_t)hc * 1024 + k);
  float4 v0 = *(const float4*)src;
  float4 v1 = *(const float4*)(src + 4);
  s16x8 r;
  r[0] = (short)f2bf(v0.x); r[1] = (short)f2bf(v0.y);
  r[2] = (short)f2bf(v0.z); r[3] = (short)f2bf(v0.w);
  r[4] = (short)f2bf(v1.x); r[5] = (short)f2bf(v1.y);
  r[6] = (short)f2bf(v1.z); r[7] = (short)f2bf(v1.w);
  *(s16x8*)(Wpk + (size_t)f * 8) = r;
}

__global__ void __launch_bounds__(256) pack_bias(
    const float* __restrict__ bii, const float* __restrict__ bhi,
    const float* __restrict__ bif, const float* __restrict__ bhf,
    const float* __restrict__ big, const float* __restrict__ bhg,
    const float* __restrict__ bio, const float* __restrict__ bho,
    float* __restrict__ biasC)
{
  int cidx = blockIdx.x * 256 + threadIdx.x;  // 0..4095
  int col = cidx & 15, blk = cidx >> 4;
  int hc = blk * 4 + (col >> 2), g = col & 3;
  const float* bi4[4] = {bii, bif, big, bio};
  const float* bh4[4] = {bhi, bhf, bhg, bho};
  biasC[cidx] = bi4[g][hc] + bh4[g][hc];
}

// x [B][S][I] fp32 -> xb [S][B][I] bf16
__global__ void __launch_bounds__(256) conv_x(const float* __restrict__ x,
                                              unsigned short* __restrict__ xb)
{
  int bs = blockIdx.x;
  int b = bs >> 9, s = bs & 511;
  float4 v = *(const float4*)(x + ((size_t)b * 512 + s) * 1024 + threadIdx.x * 4);
  *(ushort4*)(xb + ((size_t)s * 64 + b) * 1024 + threadIdx.x * 4) =
      make_ushort4(f2bf(v.x), f2bf(v.y), f2bf(v.z), f2bf(v.w));
}

// hseq [S+1][B][H] bf16 -> out hidden_seq [B][S][H] fp32
__global__ void __launch_bounds__(256) conv_out(const unsigned short* __restrict__ hseq,
                                                float* __restrict__ out)
{
  int bt = blockIdx.x;             // 0..32767
  int b = bt >> 9, t = bt & 511;
  ushort4 v = *(const ushort4*)(hseq + (size_t)(t + 1) * 65536 + b * 1024 + threadIdx.x * 4);
  float4 o;
  o.x = bf2f(v.x); o.y = bf2f(v.y); o.z = bf2f(v.z); o.w = bf2f(v.w);
  *(float4*)(out + ((size_t)b * 512 + t) * 1024 + threadIdx.x * 4) = o;
}

// ---------------------------------------------------------------------------
// Hierarchical monotone barrier (r4; probe-measured inside 2.45us skeleton).
// ---------------------------------------------------------------------------
__device__ __forceinline__ void hbar_arrive(int* cnt, int blk, int kbar) {
  int g = blk & 7;
  int* lp = cnt + g * 16;
  __hip_atomic_fetch_add(lp, 1, __ATOMIC_RELAXED, __HIP_MEMORY_SCOPE_AGENT);
  if (blk < 8) {   // master of group g == blk
    while (__hip_atomic_load(lp, __ATOMIC_RELAXED, __HIP_MEMORY_SCOPE_AGENT) < 32 * kbar)
      __builtin_amdgcn_s_sleep(1);
    __hip_atomic_fetch_add(cnt + 8 * 16, 1, __ATOMIC_RELAXED, __HIP_MEMORY_SCOPE_AGENT);
  }
}
__device__ __forceinline__ void hbar_spin(int* cnt, int kbar) {
  int* gp = cnt + 8 * 16;
  while (__hip_atomic_load(gp, __ATOMIC_RELAXED, __HIP_MEMORY_SCOPE_AGENT) < 8 * kbar)
    __builtin_amdgcn_s_sleep(1);
}

// direct-load K-half GEMM (r11-proven)
__device__ __forceinline__ void gemm_half1(const unsigned short* __restrict__ aptr,
                                           const s16x8* __restrict__ WlV, int wb,
                                           f32x4& out) {
  s16x8 a[16];
#pragma unroll
  for (int kb = 0; kb < 16; ++kb) a[kb] = *(const s16x8*)(aptr + kb * 32);
  f32x4 c0_ = {0.f, 0.f, 0.f, 0.f}, c1_ = c0_;
#pragma unroll
  for (int kb = 0; kb < 16; kb += 2) {
    c0_ = __builtin_amdgcn_mfma_f32_16x16x32_bf16(a[kb],     WlV[wb + kb * 64],       c0_, 0, 0, 0);
    c1_ = __builtin_amdgcn_mfma_f32_16x16x32_bf16(a[kb + 1], WlV[wb + (kb + 1) * 64], c1_, 0, 0, 0);
  }
  out = c0_ + c1_;
}

// ---------------------------------------------------------------------------
// Persistent LSTM v12 = r11 structure + ASYNC x-prefetch done correctly:
// T14 issue-early / consume-late. 256 blocks x 512 threads, 1 block/CU.
// Wave w: m = w&3 (batch 16-row tile), kh = w>>2 (K-half 512).
// A: ISSUE 8-frag x(t+1) DMA (global_load_lds) -> stage slot;  publish
//    xacc(t); direct-load h-GEMM(t) (~2.2us hides the DMA RTT); gH.   -> S1
// B: gate math + shfl-packed 8B agent flush.                          -> S2
// D: arrive; consume x(t+1): 8 ds_read (stage) + 8 direct + 16 MFMA
//    (~0.5us instead of 2.2); spin.                                   -> S3
// S1/S2 barrier drains guarantee DMA completion long before phase D.
// ---------------------------------------------------------------------------
__global__ void __launch_bounds__(512, 1) lstm_fast11(
    const unsigned short* __restrict__ Wpk,  // [256][2][32][64][8] bf16 (16 MB)
    const float* __restrict__ biasC,         // [256][16]
    const unsigned short* __restrict__ xb,   // [S][B][I] bf16
    unsigned short* __restrict__ hseq,       // [S+1][B][H] bf16 rotating
    int* __restrict__ cnt,                   // 9 lines x 64B, monotone
    const float* __restrict__ h0,
    const float* __restrict__ c0,
    float* __restrict__ out)                 // [hidden_seq][h_f][c_f]
{
  __shared__ s16x8 WlV[4096];                // 64 KB single-W frags
  __shared__ s16x8 stageV[4096];             // 64 KB x-prefetch stage (8KB/wave)
  __shared__ float gX[2][64][17];            // x partials per K-half
  __shared__ float gH[2][64][17];            // h partials per K-half
  __shared__ float biasLds[16];
  __shared__ short hOutLds[64][4];           // staged h_{t+1} for 8B flush

  const int tid  = threadIdx.x;
  const int blk  = blockIdx.x;
  const int wave = tid >> 6, lane = tid & 63;
  const int m  = wave & 3;        // batch tile
  const int kh = wave >> 2;       // K-half within each operand
  const int arow = m * 16 + (lane & 15);
  const int koff = (lane >> 4) * 8;
  const int aoff = arow * 1024 + kh * 512 + koff;   // element offset in a t-slot
  const int wxb = (kh * 16) * 64 + lane;            // x-part W frag base in LDS
  const int whb = (32 + kh * 16) * 64 + lane;       // h-part W frag base in LDS
  const int drow = m * 16 + (lane >> 4) * 4;
  const int dcol = lane & 15;
  s16x8* sw = stageV + wave * 512;                  // this wave's 8KB stage slot

  // stage this block's W chunk (64 KB linear; frag order == read order)
  {
    const s16x8* src = (const s16x8*)(Wpk + (size_t)blk * 32768);
#pragma unroll
    for (int it = 0; it < 8; ++it) WlV[it * 512 + tid] = src[it * 512 + tid];
  }
  if (tid < 16) biasLds[tid] = biasC[blk * 16 + tid];

  // init hseq slot 0 from h0 with agent-visible stores
  if (tid < 128) {
    int p = blk * 128 + tid;                 // pair index over B*H/2
    unsigned lo = f2bf(h0[2 * p]), hi = f2bf(h0[2 * p + 1]);
    __hip_atomic_store((unsigned*)(hseq + 2 * p), lo | (hi << 16),
                       __ATOMIC_RELAXED, __HIP_MEMORY_SCOPE_AGENT);
  }
  const int rb_batch = tid >> 2, rb_j = tid & 3;
  float c_reg = 0.f;
  if (tid < 256) c_reg = c0[rb_batch * 1024 + blk * 4 + rb_j];

  __syncthreads();                           // W staged; h0 stores drained

  // prologue: x-GEMM(0), direct loads
  f32x4 xacc;
  gemm_half1(xb + aoff, WlV, wxb, xacc);

  if (tid == 256) { hbar_arrive(cnt, blk, 1); hbar_spin(cnt, 1); }
  __syncthreads();                           // hseq slot 0 globally visible

  for (int t = 0; t < SS; ++t) {
    const unsigned short* xnext = xb + (size_t)(t + 1) * 65536 + aoff;

    // ---- phase A: ISSUE x(t+1) DMA (frags 0..7) -- consumed in phase D ----
    if (t + 1 < SS) {
#pragma unroll
      for (int j = 0; j < 8; ++j)
        __builtin_amdgcn_global_load_lds(
            (const __attribute__((address_space(1))) void*)(xnext + j * 32),
            (__attribute__((address_space(3))) void*)(sw + j * 64), 16, 0, 0);
    }

    // publish x partials for step t (computed last phase D / prologue)
#pragma unroll
    for (int r = 0; r < 4; ++r) gX[kh][drow + r][dcol] = xacc[r];

    // h-GEMM(t): direct loads; DMA RTT hides under this ~2.2us chain
    {
      f32x4 hs;
      gemm_half1(hseq + (size_t)t * 65536 + aoff, WlV, whb, hs);
#pragma unroll
      for (int r = 0; r < 4; ++r) gH[kh][drow + r][dcol] = hs[r];
    }
    __syncthreads();                         // S1 (drains vmcnt -> DMA complete)

    // ---- phase B: gate math over 4 partials + shfl-packed flush ----
    if (tid < 256) {
      int c0i = rb_j * 4;
      float si = gX[0][rb_batch][c0i + 0] + gX[1][rb_batch][c0i + 0]
               + gH[0][rb_batch][c0i + 0] + gH[1][rb_batch][c0i + 0] + biasLds[c0i + 0];
      float sf = gX[0][rb_batch][c0i + 1] + gX[1][rb_batch][c0i + 1]
               + gH[0][rb_batch][c0i + 1] + gH[1][rb_batch][c0i + 1] + biasLds[c0i + 1];
      float sg = gX[0][rb_batch][c0i + 2] + gX[1][rb_batch][c0i + 2]
               + gH[0][rb_batch][c0i + 2] + gH[1][rb_batch][c0i + 2] + biasLds[c0i + 2];
      float so = gX[0][rb_batch][c0i + 3] + gX[1][rb_batch][c0i + 3]
               + gH[0][rb_batch][c0i + 3] + gH[1][rb_batch][c0i + 3] + biasLds[c0i + 3];
      float iv = 1.f / (1.f + __expf(-si));
      float fv = 1.f / (1.f + __expf(-sf));
      float gv = tanhf(sg);
      float ov = 1.f / (1.f + __expf(-so));
      c_reg = fv * c_reg + iv * gv;
      float hv = ov * tanhf(c_reg);
      hOutLds[rb_batch][rb_j] = (short)f2bf(hv);
      if (t == SS - 1) {
        int hcg = blk * 4 + rb_j;
        out[(size_t)BB * SS * HH + rb_batch * 1024 + hcg] = hv;            // h_f fp32
        out[(size_t)BB * SS * HH + 65536 + rb_batch * 1024 + hcg] = c_reg; // c_f fp32
      }
    }
    __syncthreads();                         // S2

    // ---- phase C: flush h_{t+1} (64 x 8B agent stores) ----
    if (tid < 64) {
      unsigned long long v = *(const unsigned long long*)&hOutLds[tid][0];
      __hip_atomic_store(
          (unsigned long long*)(hseq + (size_t)(t + 1) * 65536 + tid * 1024 + blk * 4),
          v, __ATOMIC_RELAXED, __HIP_MEMORY_SCOPE_AGENT);
    }
    __syncthreads();                         // S3: flush drained per thread

    // ---- phase D: arrive; CONSUME x(t+1) (cheap); spin ----
    if (t + 1 < SS) {
      if (tid == 256) hbar_arrive(cnt, blk, t + 2);
      // direct-load frags 8..15 (one burst, ~1 RTT)
      s16x8 a8[8];
#pragma unroll
      for (int j = 0; j < 8; ++j) a8[j] = *(const s16x8*)(xnext + (8 + j) * 32);
      // frags 0..7 from the DMA stage (already resident; ds_read only)
      s16x8 s8[8];
#pragma unroll
      for (int j = 0; j < 8; ++j) s8[j] = sw[j * 64 + lane];
      f32x4 c0_ = {0.f, 0.f, 0.f, 0.f}, c1_ = c0_;
#pragma unroll
      for (int j = 0; j < 8; j += 2) {
        c0_ = __builtin_amdgcn_mfma_f32_16x16x32_bf16(s8[j],     WlV[wxb + j * 64],       c0_, 0, 0, 0);
        c1_ = __builtin_amdgcn_mfma_f32_16x16x32_bf16(s8[j + 1], WlV[wxb + (j + 1) * 64], c1_, 0, 0, 0);
      }
#pragma unroll
      for (int j = 0; j < 8; j += 2) {
        c0_ = __builtin_amdgcn_mfma_f32_16x16x32_bf16(a8[j],     WlV[wxb + (8 + j) * 64], c0_, 0, 0, 0);
        c1_ = __builtin_amdgcn_mfma_f32_16x16x32_bf16(a8[j + 1], WlV[wxb + (9 + j) * 64], c1_, 0, 0, 0);
      }
      xacc = c0_ + c1_;
      if (tid == 256) hbar_spin(cnt, t + 2);
      __syncthreads();                       // S4: h_{t+1} globally visible
    }
  }
}

// ---------------------------------------------------------------------------
// LEGACY fallback (cg::grid.sync) for small ws_size. Unchanged.
// ---------------------------------------------------------------------------
__global__ void __launch_bounds__(256) pack_w(
    const float* __restrict__ wii, const float* __restrict__ whi_,
    const float* __restrict__ wif, const float* __restrict__ whf,
    const float* __restrict__ wig, const float* __restrict__ whg,
    const float* __restrict__ wio, const float* __restrict__ who,
    unsigned short* __restrict__ Whi, unsigned short* __restrict__ Wlo)
{
  size_t idx = ((size_t)blockIdx.x * 256 + threadIdx.x) * 4;
  int k   = (int)(idx & 2047);
  int rg  = (int)(idx >> 11);
  int row = rg & 15;
  int blk = rg >> 4;
  int hc  = blk * 4 + (row >> 2);
  int g   = row & 3;
  const float* wi4[4] = {wii, wif, wig, wio};
  const float* wh4[4] = {whi_, whf, whg, who};
  const float* src = (k < 1024) ? (wi4[g] + (size_t)hc * 1024 + k)
                                : (wh4[g] + (size_t)hc * 1024 + (k - 1024));
  float4 v = *(const float4*)src;
  float vv[4] = {v.x, v.y, v.z, v.w};
  unsigned short h_[4], l_[4];
#pragma unroll
  for (int j = 0; j < 4; ++j) {
    unsigned short h = f2bf(vv[j]);
    h_[j] = h;
    l_[j] = f2bf(vv[j] - bf2f(h));
  }
  *(ushort4*)(Whi + idx) = make_ushort4(h_[0], h_[1], h_[2], h_[3]);
  *(ushort4*)(Wlo + idx) = make_ushort4(l_[0], l_[1], l_[2], l_[3]);
}

__global__ void __launch_bounds__(512, 1) lstm_seq_legacy(
    const unsigned short* __restrict__ W,
    const float* __restrict__ biasC,
    const float* __restrict__ xin,
    unsigned short* __restrict__ hb,
    const float* __restrict__ h0,
    const float* __restrict__ c0,
    float* __restrict__ out)
{
  __shared__ short Wl[2][16][2048];
  __shared__ float gLds[2][64][17];
  __shared__ float biasLds[16];

  const int tid  = threadIdx.x;
  const int blk  = blockIdx.x;
  const int wave = tid >> 6;
  const int lane = tid & 63;
  const int m    = wave >> 1;
  const int ks   = wave & 1;
  const int arow = m * 16 + (lane & 15);
  const int koff = (lane >> 4) * 8;
  const int brow = lane & 15;
  const int bswz = (brow & 7) << 4;

  {
    const char* srcH = (const char*)W + (size_t)blk * 65536;
    const char* srcL = (const char*)W + 16777216u + (size_t)blk * 65536;
    char* dstH = (char*)&Wl[0][0][0];
    char* dstL = (char*)&Wl[1][0][0];
#pragma unroll
    for (int it = 0; it < 8; ++it) {
      int boff = it * 8192 + tid * 16;
      int row  = boff >> 12;
      int colb = boff & 4095;
      int dsw  = row * 4096 + (colb ^ ((row & 7) << 4));
      *(int4*)(dstH + dsw) = *(const int4*)(srcH + boff);
      *(int4*)(dstL + dsw) = *(const int4*)(srcL + boff);
    }
  }
  if (tid < 16) biasLds[tid] = biasC[blk * 16 + tid];
  if (tid < 256) {
    int e = blk * 256 + tid;
    hb[e] = f2bf(h0[e]);
  }
  const int rb_batch = tid >> 2, rb_j = tid & 3;
  float c_reg = 0.f;
  if (tid < 256) c_reg = c0[rb_batch * 1024 + blk * 4 + rb_j];

  cg::grid_group grid = cg::this_grid();
  __syncthreads();
  grid.sync();

  const char* wrow = (const char*)&Wl[0][0][0] + brow * 4096;
  const int kbyte = ks * 2048;

  for (int t = 0; t < SS; ++t) {
    const unsigned short* hcur = hb + (t & 1) * 65536;
    f32x4 accH = {0.f, 0.f, 0.f, 0.f};
    f32x4 accL = {0.f, 0.f, 0.f, 0.f};

    if (ks == 1) {
      const unsigned short* aptr = hcur + arow * 1024 + koff;
#pragma unroll
      for (int kk = 0; kk < 1024; kk += 32) {
        s16x8 a = *(const s16x8*)(aptr + kk);
        int cb = (kbyte + (kk + koff) * 2) ^ bswz;
        s16x8 bh = *(const s16x8*)(wrow + cb);
        s16x8 bl = *(const s16x8*)(wrow + 65536 + cb);
        accH = __builtin_amdgcn_mfma_f32_16x16x32_bf16(a, bh, accH, 0, 0, 0);
        accL = __builtin_amdgcn_mfma_f32_16x16x32_bf16(a, bl, accL, 0, 0, 0);
      }
    } else {
      const float* xp = xin + ((size_t)arow * 512 + t) * 1024 + koff;
#pragma unroll
      for (int kk = 0; kk < 1024; kk += 32) {
        float4 f0 = *(const float4*)(xp + kk);
        float4 f1 = *(const float4*)(xp + kk + 4);
        s16x8 a;
        a[0] = (short)f2bf(f0.x); a[1] = (short)f2bf(f0.y);
        a[2] = (short)f2bf(f0.z); a[3] = (short)f2bf(f0.w);
        a[4] = (short)f2bf(f1.x); a[5] = (short)f2bf(f1.y);
        a[6] = (short)f2bf(f1.z); a[7] = (short)f2bf(f1.w);
        int cb = ((kk + koff) * 2) ^ bswz;
        s16x8 bh = *(const s16x8*)(wrow + cb);
        s16x8 bl = *(const s16x8*)(wrow + 65536 + cb);
        accH = __builtin_amdgcn_mfma_f32_16x16x32_bf16(a, bh, accH, 0, 0, 0);
        accL = __builtin_amdgcn_mfma_f32_16x16x32_bf16(a, bl, accL, 0, 0, 0);
      }
    }

    {
      f32x4 acc = accH + accL;
      int drow = m * 16 + (lane >> 4) * 4;
      int dcol = lane & 15;
#pragma unroll
      for (int r = 0; r < 4; ++r) gLds[ks][drow + r][dcol] = acc[r];
    }
    __syncthreads();

    if (tid < 256) {
      int c0i = rb_j * 4;
      float si = gLds[0][rb_batch][c0i + 0] + gLds[1][rb_batch][c0i + 0] + biasLds[c0i + 0];
      float sf = gLds[0][rb_batch][c0i + 1] + gLds[1][rb_batch][c0i + 1] + biasLds[c0i + 1];
      float sg = gLds[0][rb_batch][c0i + 2] + gLds[1][rb_batch][c0i + 2] + biasLds[c0i + 2];
      float so = gLds[0][rb_batch][c0i + 3] + gLds[1][rb_batch][c0i + 3] + biasLds[c0i + 3];
      float iv = 1.f / (1.f + __expf(-si));
      float fv = 1.f / (1.f + __expf(-sf));
      float gv = tanhf(sg);
      float ov = 1.f / (1.f + __expf(-so));
      c_reg = fv * c_reg + iv * gv;
      float hv = ov * tanhf(c_reg);
      int hcg = blk * 4 + rb_j;
      out[(size_t)rb_batch * (SS * HH) + (size_t)t * HH + hcg] = hv;
      hb[((t + 1) & 1) * 65536 + rb_batch * 1024 + hcg] = f2bf(hv);
      if (t == SS - 1) {
        out[(size_t)BB * SS * HH + rb_batch * 1024 + hcg] = hv;
        out[(size_t)BB * SS * HH + 65536 + rb_batch * 1024 + hcg] = c_reg;
      }
    }
    grid.sync();
  }
}

extern "C" void kernel_launch(void* const* d_in, const int* in_sizes, int n_in,
                              void* d_out, int out_size, void* d_ws, size_t ws_size,
                              hipStream_t stream) {
  const float* xin = (const float*)d_in[0];
  const float* h0  = (const float*)d_in[1];
  const float* c0  = (const float*)d_in[2];
  const float* wii = (const float*)d_in[3];
  const float* whi = (const float*)d_in[4];
  const float* bii = (const float*)d_in[5];
  const float* bhi = (const float*)d_in[6];
  const float* wif = (const float*)d_in[7];
  const float* whf = (const float*)d_in[8];
  const float* bif = (const float*)d_in[9];
  const float* bhf = (const float*)d_in[10];
  const float* wig = (const float*)d_in[11];
  const float* whg = (const float*)d_in[12];
  const float* big = (const float*)d_in[13];
  const float* bhg = (const float*)d_in[14];
  const float* wio = (const float*)d_in[15];
  const float* who = (const float*)d_in[16];
  const float* bio = (const float*)d_in[17];
  const float* bho = (const float*)d_in[18];
  float* out = (float*)d_out;

  char* ws = (char*)d_ws;
  // fast layout (same offsets as r2-r12; Wpk uses 16 MB of its 32 MB slot)
  unsigned short* Wpk   = (unsigned short*)ws;                 // 16 MB
  float*          biasC = (float*)(ws + 33554432);             // 16 KB
  int*            cnt   = (int*)(ws + 33570816);               // 64 KB slot (uses 576 B)
  unsigned short* hseq  = (unsigned short*)(ws + 33636352);    // 513*131072
  unsigned short* xb    = (unsigned short*)(ws + 100876288);   // 64 MB
  const size_t need_fast_xb = 100876288ull + 67108864ull;      // 167985152

  // legacy layout
  unsigned short* Wl_  = (unsigned short*)ws;                  // 32 MB hi+lo
  unsigned short* hb   = (unsigned short*)(ws + 33570816);     // 256 KB

  if (ws_size >= need_fast_xb) {
    pack_w_single<<<4096, 256, 0, stream>>>(wii, whi, wif, whf, wig, whg, wio, who, Wpk);
    pack_bias<<<16, 256, 0, stream>>>(bii, bhi, bif, bhf, big, bhg, bio, bho, biasC);
    conv_x<<<32768, 256, 0, stream>>>(xin, xb);
    hipMemsetAsync(cnt, 0, 4096, stream);

    void* ka[] = {(void*)&Wpk, (void*)&biasC, (void*)&xb,
                  (void*)&hseq, (void*)&cnt, (void*)&h0, (void*)&c0, (void*)&out};
    hipLaunchCooperativeKernel(reinterpret_cast<const void*>(&lstm_fast11),
                               dim3(256), dim3(512), ka, 0, stream);
    conv_out<<<32768, 256, 0, stream>>>(hseq, out);
  } else {
    pack_w<<<8192, 256, 0, stream>>>(wii, whi, wif, whf, wig, whg, wio, who,
                                     Wl_, Wl_ + 8388608);
    pack_bias<<<16, 256, 0, stream>>>(bii, bhi, bif, bhf, big, bhg, bio, bho, biasC);
    void* ka[] = {(void*)&Wl_, (void*)&biasC, (void*)&xin,
                  (void*)&hb, (void*)&h0, (void*)&c0, (void*)&out};
    hipLaunchCooperativeKernel(reinterpret_cast<const void*>(&lstm_seq_legacy),
                               dim3(256), dim3(512), ka, 0, stream);
  }
}

// Round 14
// 4357.301 us; speedup vs baseline: 1.0654x; 1.0194x over previous
//
#include <hip/hip_runtime.h>
#include <hip/hip_bf16.h>
#include <hip/hip_cooperative_groups.h>

namespace cg = cooperative_groups;

using s16x8 = __attribute__((ext_vector_type(8))) short;   // 8 bf16 (4 VGPRs) MFMA frag
using f32x4 = __attribute__((ext_vector_type(4))) float;   // MFMA accumulator

constexpr int BB = 64;    // batch
constexpr int SS = 512;   // seq len
constexpr int II = 1024;  // input dim
constexpr int HH = 1024;  // hidden dim

__device__ __forceinline__ unsigned short f2bf(float f) {
  unsigned u = __float_as_uint(f);
  unsigned r = u + 0x7fffu + ((u >> 16) & 1u);   // RN-even
  return (unsigned short)(r >> 16);
}
__device__ __forceinline__ float bf2f(unsigned short h) {
  return __uint_as_float(((unsigned)h) << 16);
}

// ---------------------------------------------------------------------------
// Single bf16 W in MFMA-linear fragment order (16 MB):
// Wpk[blk 256][ks 2][kb 32][lane 64][e 8]; lane: n=lane&15 (gate-row), u=lane>>4;
// element k (within ks-part) = kb*32 + u*8 + e.
// ---------------------------------------------------------------------------
__global__ void __launch_bounds__(256) pack_w_single(
    const float* __restrict__ wii, const float* __restrict__ whi_,
    const float* __restrict__ wif, const float* __restrict__ whf,
    const float* __restrict__ wig, const float* __restrict__ whg,
    const float* __restrict__ wio, const float* __restrict__ who,
    unsigned short* __restrict__ Wpk)
{
  unsigned f = blockIdx.x * 256 + threadIdx.x;   // frag id, 0..1048575
  int lane = f & 63;
  int kb   = (f >> 6) & 31;
  int ks   = (f >> 11) & 1;
  int blk  = (int)(f >> 12);
  int n = lane & 15, u = lane >> 4;
  int hc = blk * 4 + (n >> 2), g = n & 3;
  int k  = kb * 32 + u * 8;
  const float* wi4[4] = {wii, wif, wig, wio};
  const float* wh4[4] = {whi_, whf, whg, who};
  const float* src = (ks == 0) ? (wi4[g] + (size_t)hc * 1024 + k)
                               : (wh4[g] + (size_t)hc * 1024 + k);
  float4 v0 = *(const float4*)src;
  float4 v1 = *(const float4*)(src + 4);
  s16x8 r;
  r[0] = (short)f2bf(v0.x); r[1] = (short)f2bf(v0.y);
  r[2] = (short)f2bf(v0.z); r[3] = (short)f2bf(v0.w);
  r[4] = (short)f2bf(v1.x); r[5] = (short)f2bf(v1.y);
  r[6] = (short)f2bf(v1.z); r[7] = (short)f2bf(v1.w);
  *(s16x8*)(Wpk + (size_t)f * 8) = r;
}

__global__ void __launch_bounds__(256) pack_bias(
    const float* __restrict__ bii, const float* __restrict__ bhi,
    const float* __restrict__ bif, const float* __restrict__ bhf,
    const float* __restrict__ big, const float* __restrict__ bhg,
    const float* __restrict__ bio, const float* __restrict__ bho,
    float* __restrict__ biasC)
{
  int cidx = blockIdx.x * 256 + threadIdx.x;  // 0..4095
  int col = cidx & 15, blk = cidx >> 4;
  int hc = blk * 4 + (col >> 2), g = col & 3;
  const float* bi4[4] = {bii, bif, big, bio};
  const float* bh4[4] = {bhi, bhf, bhg, bho};
  biasC[cidx] = bi4[g][hc] + bh4[g][hc];
}

// x [B][S][I] fp32 -> xb [S][B][I] bf16
__global__ void __launch_bounds__(256) conv_x(const float* __restrict__ x,
                                              unsigned short* __restrict__ xb)
{
  int bs = blockIdx.x;
  int b = bs >> 9, s = bs & 511;
  float4 v = *(const float4*)(x + ((size_t)b * 512 + s) * 1024 + threadIdx.x * 4);
  *(ushort4*)(xb + ((size_t)s * 64 + b) * 1024 + threadIdx.x * 4) =
      make_ushort4(f2bf(v.x), f2bf(v.y), f2bf(v.z), f2bf(v.w));
}

// hseq [S+1][B][H] bf16 -> out hidden_seq [B][S][H] fp32
__global__ void __launch_bounds__(256) conv_out(const unsigned short* __restrict__ hseq,
                                                float* __restrict__ out)
{
  int bt = blockIdx.x;             // 0..32767
  int b = bt >> 9, t = bt & 511;
  ushort4 v = *(const ushort4*)(hseq + (size_t)(t + 1) * 65536 + b * 1024 + threadIdx.x * 4);
  float4 o;
  o.x = bf2f(v.x); o.y = bf2f(v.y); o.z = bf2f(v.z); o.w = bf2f(v.w);
  *(float4*)(out + ((size_t)b * 512 + t) * 1024 + threadIdx.x * 4) = o;
}

// ---------------------------------------------------------------------------
// Hierarchical monotone barrier (r4; probe-measured inside 2.45us skeleton).
// ---------------------------------------------------------------------------
__device__ __forceinline__ void hbar_arrive(int* cnt, int blk, int kbar) {
  int g = blk & 7;
  int* lp = cnt + g * 16;
  __hip_atomic_fetch_add(lp, 1, __ATOMIC_RELAXED, __HIP_MEMORY_SCOPE_AGENT);
  if (blk < 8) {   // master of group g == blk
    while (__hip_atomic_load(lp, __ATOMIC_RELAXED, __HIP_MEMORY_SCOPE_AGENT) < 32 * kbar)
      __builtin_amdgcn_s_sleep(1);
    __hip_atomic_fetch_add(cnt + 8 * 16, 1, __ATOMIC_RELAXED, __HIP_MEMORY_SCOPE_AGENT);
  }
}
__device__ __forceinline__ void hbar_spin(int* cnt, int kbar) {
  int* gp = cnt + 8 * 16;
  while (__hip_atomic_load(gp, __ATOMIC_RELAXED, __HIP_MEMORY_SCOPE_AGENT) < 8 * kbar)
    __builtin_amdgcn_s_sleep(1);
}

// ---------------------------------------------------------------------------
// K-quarter GEMM: 8 frag loads (32 VGPR -- small enough that the FULL burst
// stays in flight within the compiler's ~88-VGPR envelope -> one RTT window),
// 8 ds_read_b128 + 8 MFMAs.
// ---------------------------------------------------------------------------
__device__ __forceinline__ void gemm_q(const unsigned short* __restrict__ aptr,
                                       const s16x8* __restrict__ WlV, int wb,
                                       f32x4& out) {
  s16x8 a[8];
#pragma unroll
  for (int kb = 0; kb < 8; ++kb) a[kb] = *(const s16x8*)(aptr + kb * 32);
  f32x4 c0_ = {0.f, 0.f, 0.f, 0.f}, c1_ = c0_;
#pragma unroll
  for (int kb = 0; kb < 8; kb += 2) {
    c0_ = __builtin_amdgcn_mfma_f32_16x16x32_bf16(a[kb],     WlV[wb + kb * 64],       c0_, 0, 0, 0);
    c1_ = __builtin_amdgcn_mfma_f32_16x16x32_bf16(a[kb + 1], WlV[wb + (kb + 1) * 64], c1_, 0, 0, 0);
  }
  out = c0_ + c1_;
}

// ---------------------------------------------------------------------------
// Persistent LSTM v13 = r11 structure with 16 waves / K-quartered GEMMs.
// 256 blocks x 1024 threads, 1 block/CU (LDS ~99KB).
// Wave w: m = w&3 (batch 16-row tile), kq = w>>2 (K-quarter, 256 elems).
// A: publish xacc(t); K-quarter h-GEMM(t) (8-load single-RTT burst).  -> S1
// B: gate math sums 8 partials (gX[0..3], gH[0..3]) + bias.           -> S2
// C: flush h_{t+1} (64 x 8B agent stores).                            -> S3
// D: arrive; K-quarter x-GEMM(t+1) under the wait (r13: fully hidden);
//    spin.                                                            -> S4
// ---------------------------------------------------------------------------
__global__ void __launch_bounds__(1024, 1) lstm_fast12(
    const unsigned short* __restrict__ Wpk,  // [256][2][32][64][8] bf16 (16 MB)
    const float* __restrict__ biasC,         // [256][16]
    const unsigned short* __restrict__ xb,   // [S][B][I] bf16
    unsigned short* __restrict__ hseq,       // [S+1][B][H] bf16 rotating
    int* __restrict__ cnt,                   // 9 lines x 64B, monotone
    const float* __restrict__ h0,
    const float* __restrict__ c0,
    float* __restrict__ out)                 // [hidden_seq][h_f][c_f]
{
  __shared__ s16x8 WlV[4096];                // 64 KB single-W frags
  __shared__ float gX[4][64][17];            // x partials per K-quarter (17.0 KB)
  __shared__ float gH[4][64][17];            // h partials per K-quarter (17.0 KB)
  __shared__ float biasLds[16];
  __shared__ short hOutLds[64][4];           // staged h_{t+1} for 8B flush

  const int tid  = threadIdx.x;
  const int blk  = blockIdx.x;
  const int wave = tid >> 6, lane = tid & 63;
  const int m  = wave & 3;        // batch tile
  const int kq = wave >> 2;       // K-quarter within each operand (0..3)
  const int arow = m * 16 + (lane & 15);
  const int koff = (lane >> 4) * 8;
  const int aoff = arow * 1024 + kq * 256 + koff;   // element offset in a t-slot
  const int wxb = (kq * 8) * 64 + lane;             // x-part W frag base in LDS
  const int whb = (32 + kq * 8) * 64 + lane;        // h-part W frag base in LDS
  const int drow = m * 16 + (lane >> 4) * 4;
  const int dcol = lane & 15;

  // stage this block's W chunk (64 KB linear; frag order == read order)
  {
    const s16x8* src = (const s16x8*)(Wpk + (size_t)blk * 32768);
#pragma unroll
    for (int it = 0; it < 4; ++it) WlV[it * 1024 + tid] = src[it * 1024 + tid];
  }
  if (tid < 16) biasLds[tid] = biasC[blk * 16 + tid];

  // init hseq slot 0 from h0 with agent-visible stores
  if (tid < 128) {
    int p = blk * 128 + tid;                 // pair index over B*H/2
    unsigned lo = f2bf(h0[2 * p]), hi = f2bf(h0[2 * p + 1]);
    __hip_atomic_store((unsigned*)(hseq + 2 * p), lo | (hi << 16),
                       __ATOMIC_RELAXED, __HIP_MEMORY_SCOPE_AGENT);
  }
  const int rb_batch = tid >> 2, rb_j = tid & 3;
  float c_reg = 0.f;
  if (tid < 256) c_reg = c0[rb_batch * 1024 + blk * 4 + rb_j];

  __syncthreads();                           // W staged; h0 stores drained

  // prologue: x-GEMM(0) on all 16 waves (K-quartered)
  f32x4 xacc;
  gemm_q(xb + aoff, WlV, wxb, xacc);

  if (tid == 256) { hbar_arrive(cnt, blk, 1); hbar_spin(cnt, 1); }
  __syncthreads();                           // hseq slot 0 globally visible

  for (int t = 0; t < SS; ++t) {
    // ---- phase A: publish xacc(t); K-quarter h-GEMM(t); publish h partials ----
#pragma unroll
    for (int r = 0; r < 4; ++r) gX[kq][drow + r][dcol] = xacc[r];
    {
      f32x4 hs;
      gemm_q(hseq + (size_t)t * 65536 + aoff, WlV, whb, hs);
#pragma unroll
      for (int r = 0; r < 4; ++r) gH[kq][drow + r][dcol] = hs[r];
    }
    __syncthreads();                         // S1

    // ---- phase B: gate math over 8 partials ----
    if (tid < 256) {
      int c0i = rb_j * 4;
      float si = (gX[0][rb_batch][c0i + 0] + gX[1][rb_batch][c0i + 0])
               + (gX[2][rb_batch][c0i + 0] + gX[3][rb_batch][c0i + 0])
               + (gH[0][rb_batch][c0i + 0] + gH[1][rb_batch][c0i + 0])
               + (gH[2][rb_batch][c0i + 0] + gH[3][rb_batch][c0i + 0]) + biasLds[c0i + 0];
      float sf = (gX[0][rb_batch][c0i + 1] + gX[1][rb_batch][c0i + 1])
               + (gX[2][rb_batch][c0i + 1] + gX[3][rb_batch][c0i + 1])
               + (gH[0][rb_batch][c0i + 1] + gH[1][rb_batch][c0i + 1])
               + (gH[2][rb_batch][c0i + 1] + gH[3][rb_batch][c0i + 1]) + biasLds[c0i + 1];
      float sg = (gX[0][rb_batch][c0i + 2] + gX[1][rb_batch][c0i + 2])
               + (gX[2][rb_batch][c0i + 2] + gX[3][rb_batch][c0i + 2])
               + (gH[0][rb_batch][c0i + 2] + gH[1][rb_batch][c0i + 2])
               + (gH[2][rb_batch][c0i + 2] + gH[3][rb_batch][c0i + 2]) + biasLds[c0i + 2];
      float so = (gX[0][rb_batch][c0i + 3] + gX[1][rb_batch][c0i + 3])
               + (gX[2][rb_batch][c0i + 3] + gX[3][rb_batch][c0i + 3])
               + (gH[0][rb_batch][c0i + 3] + gH[1][rb_batch][c0i + 3])
               + (gH[2][rb_batch][c0i + 3] + gH[3][rb_batch][c0i + 3]) + biasLds[c0i + 3];
      float iv = 1.f / (1.f + __expf(-si));
      float fv = 1.f / (1.f + __expf(-sf));
      float gv = tanhf(sg);
      float ov = 1.f / (1.f + __expf(-so));
      c_reg = fv * c_reg + iv * gv;
      float hv = ov * tanhf(c_reg);
      hOutLds[rb_batch][rb_j] = (short)f2bf(hv);
      if (t == SS - 1) {
        int hcg = blk * 4 + rb_j;
        out[(size_t)BB * SS * HH + rb_batch * 1024 + hcg] = hv;            // h_f fp32
        out[(size_t)BB * SS * HH + 65536 + rb_batch * 1024 + hcg] = c_reg; // c_f fp32
      }
    }
    __syncthreads();                         // S2

    // ---- phase C: flush h_{t+1} (64 x 8B agent stores) ----
    if (tid < 64) {
      unsigned long long v = *(const unsigned long long*)&hOutLds[tid][0];
      __hip_atomic_store(
          (unsigned long long*)(hseq + (size_t)(t + 1) * 65536 + tid * 1024 + blk * 4),
          v, __ATOMIC_RELAXED, __HIP_MEMORY_SCOPE_AGENT);
    }
    __syncthreads();                         // S3: flush drained per thread

    // ---- phase D: arrive; x-GEMM(t+1) under the wait; spin ----
    if (t + 1 < SS) {
      if (tid == 256) hbar_arrive(cnt, blk, t + 2);
      gemm_q(xb + (size_t)(t + 1) * 65536 + aoff, WlV, wxb, xacc);
      if (tid == 256) hbar_spin(cnt, t + 2);
      __syncthreads();                       // S4: h_{t+1} globally visible
    }
  }
}

// ---------------------------------------------------------------------------
// LEGACY fallback (cg::grid.sync) for small ws_size. Unchanged.
// ---------------------------------------------------------------------------
__global__ void __launch_bounds__(256) pack_w(
    const float* __restrict__ wii, const float* __restrict__ whi_,
    const float* __restrict__ wif, const float* __restrict__ whf,
    const float* __restrict__ wig, const float* __restrict__ whg,
    const float* __restrict__ wio, const float* __restrict__ who,
    unsigned short* __restrict__ Whi, unsigned short* __restrict__ Wlo)
{
  size_t idx = ((size_t)blockIdx.x * 256 + threadIdx.x) * 4;
  int k   = (int)(idx & 2047);
  int rg  = (int)(idx >> 11);
  int row = rg & 15;
  int blk = rg >> 4;
  int hc  = blk * 4 + (row >> 2);
  int g   = row & 3;
  const float* wi4[4] = {wii, wif, wig, wio};
  const float* wh4[4] = {whi_, whf, whg, who};
  const float* src = (k < 1024) ? (wi4[g] + (size_t)hc * 1024 + k)
                                : (wh4[g] + (size_t)hc * 1024 + (k - 1024));
  float4 v = *(const float4*)src;
  float vv[4] = {v.x, v.y, v.z, v.w};
  unsigned short h_[4], l_[4];
#pragma unroll
  for (int j = 0; j < 4; ++j) {
    unsigned short h = f2bf(vv[j]);
    h_[j] = h;
    l_[j] = f2bf(vv[j] - bf2f(h));
  }
  *(ushort4*)(Whi + idx) = make_ushort4(h_[0], h_[1], h_[2], h_[3]);
  *(ushort4*)(Wlo + idx) = make_ushort4(l_[0], l_[1], l_[2], l_[3]);
}

__global__ void __launch_bounds__(512, 1) lstm_seq_legacy(
    const unsigned short* __restrict__ W,
    const float* __restrict__ biasC,
    const float* __restrict__ xin,
    unsigned short* __restrict__ hb,
    const float* __restrict__ h0,
    const float* __restrict__ c0,
    float* __restrict__ out)
{
  __shared__ short Wl[2][16][2048];
  __shared__ float gLds[2][64][17];
  __shared__ float biasLds[16];

  const int tid  = threadIdx.x;
  const int blk  = blockIdx.x;
  const int wave = tid >> 6;
  const int lane = tid & 63;
  const int m    = wave >> 1;
  const int ks   = wave & 1;
  const int arow = m * 16 + (lane & 15);
  const int koff = (lane >> 4) * 8;
  const int brow = lane & 15;
  const int bswz = (brow & 7) << 4;

  {
    const char* srcH = (const char*)W + (size_t)blk * 65536;
    const char* srcL = (const char*)W + 16777216u + (size_t)blk * 65536;
    char* dstH = (char*)&Wl[0][0][0];
    char* dstL = (char*)&Wl[1][0][0];
#pragma unroll
    for (int it = 0; it < 8; ++it) {
      int boff = it * 8192 + tid * 16;
      int row  = boff >> 12;
      int colb = boff & 4095;
      int dsw  = row * 4096 + (colb ^ ((row & 7) << 4));
      *(int4*)(dstH + dsw) = *(const int4*)(srcH + boff);
      *(int4*)(dstL + dsw) = *(const int4*)(srcL + boff);
    }
  }
  if (tid < 16) biasLds[tid] = biasC[blk * 16 + tid];
  if (tid < 256) {
    int e = blk * 256 + tid;
    hb[e] = f2bf(h0[e]);
  }
  const int rb_batch = tid >> 2, rb_j = tid & 3;
  float c_reg = 0.f;
  if (tid < 256) c_reg = c0[rb_batch * 1024 + blk * 4 + rb_j];

  cg::grid_group grid = cg::this_grid();
  __syncthreads();
  grid.sync();

  const char* wrow = (const char*)&Wl[0][0][0] + brow * 4096;
  const int kbyte = ks * 2048;

  for (int t = 0; t < SS; ++t) {
    const unsigned short* hcur = hb + (t & 1) * 65536;
    f32x4 accH = {0.f, 0.f, 0.f, 0.f};
    f32x4 accL = {0.f, 0.f, 0.f, 0.f};

    if (ks == 1) {
      const unsigned short* aptr = hcur + arow * 1024 + koff;
#pragma unroll
      for (int kk = 0; kk < 1024; kk += 32) {
        s16x8 a = *(const s16x8*)(aptr + kk);
        int cb = (kbyte + (kk + koff) * 2) ^ bswz;
        s16x8 bh = *(const s16x8*)(wrow + cb);
        s16x8 bl = *(const s16x8*)(wrow + 65536 + cb);
        accH = __builtin_amdgcn_mfma_f32_16x16x32_bf16(a, bh, accH, 0, 0, 0);
        accL = __builtin_amdgcn_mfma_f32_16x16x32_bf16(a, bl, accL, 0, 0, 0);
      }
    } else {
      const float* xp = xin + ((size_t)arow * 512 + t) * 1024 + koff;
#pragma unroll
      for (int kk = 0; kk < 1024; kk += 32) {
        float4 f0 = *(const float4*)(xp + kk);
        float4 f1 = *(const float4*)(xp + kk + 4);
        s16x8 a;
        a[0] = (short)f2bf(f0.x); a[1] = (short)f2bf(f0.y);
        a[2] = (short)f2bf(f0.z); a[3] = (short)f2bf(f0.w);
        a[4] = (short)f2bf(f1.x); a[5] = (short)f2bf(f1.y);
        a[6] = (short)f2bf(f1.z); a[7] = (short)f2bf(f1.w);
        int cb = ((kk + koff) * 2) ^ bswz;
        s16x8 bh = *(const s16x8*)(wrow + cb);
        s16x8 bl = *(const s16x8*)(wrow + 65536 + cb);
        accH = __builtin_amdgcn_mfma_f32_16x16x32_bf16(a, bh, accH, 0, 0, 0);
        accL = __builtin_amdgcn_mfma_f32_16x16x32_bf16(a, bl, accL, 0, 0, 0);
      }
    }

    {
      f32x4 acc = accH + accL;
      int drow = m * 16 + (lane >> 4) * 4;
      int dcol = lane & 15;
#pragma unroll
      for (int r = 0; r < 4; ++r) gLds[ks][drow + r][dcol] = acc[r];
    }
    __syncthreads();

    if (tid < 256) {
      int c0i = rb_j * 4;
      float si = gLds[0][rb_batch][c0i + 0] + gLds[1][rb_batch][c0i + 0] + biasLds[c0i + 0];
      float sf = gLds[0][rb_batch][c0i + 1] + gLds[1][rb_batch][c0i + 1] + biasLds[c0i + 1];
      float sg = gLds[0][rb_batch][c0i + 2] + gLds[1][rb_batch][c0i + 2] + biasLds[c0i + 2];
      float so = gLds[0][rb_batch][c0i + 3] + gLds[1][rb_batch][c0i + 3] + biasLds[c0i + 3];
      float iv = 1.f / (1.f + __expf(-si));
      float fv = 1.f / (1.f + __expf(-sf));
      float gv = tanhf(sg);
      float ov = 1.f / (1.f + __expf(-so));
      c_reg = fv * c_reg + iv * gv;
      float hv = ov * tanhf(c_reg);
      int hcg = blk * 4 + rb_j;
      out[(size_t)rb_batch * (SS * HH) + (size_t)t * HH + hcg] = hv;
      hb[((t + 1) & 1) * 65536 + rb_batch * 1024 + hcg] = f2bf(hv);
      if (t == SS - 1) {
        out[(size_t)BB * SS * HH + rb_batch * 1024 + hcg] = hv;
        out[(size_t)BB * SS * HH + 65536 + rb_batch * 1024 + hcg] = c_reg;
      }
    }
    grid.sync();
  }
}

extern "C" void kernel_launch(void* const* d_in, const int* in_sizes, int n_in,
                              void* d_out, int out_size, void* d_ws, size_t ws_size,
                              hipStream_t stream) {
  const float* xin = (const float*)d_in[0];
  const float* h0  = (const float*)d_in[1];
  const float* c0  = (const float*)d_in[2];
  const float* wii = (const float*)d_in[3];
  const float* whi = (const float*)d_in[4];
  const float* bii = (const float*)d_in[5];
  const float* bhi = (const float*)d_in[6];
  const float* wif = (const float*)d_in[7];
  const float* whf = (const float*)d_in[8];
  const float* bif = (const float*)d_in[9];
  const float* bhf = (const float*)d_in[10];
  const float* wig = (const float*)d_in[11];
  const float* whg = (const float*)d_in[12];
  const float* big = (const float*)d_in[13];
  const float* bhg = (const float*)d_in[14];
  const float* wio = (const float*)d_in[15];
  const float* who = (const float*)d_in[16];
  const float* bio = (const float*)d_in[17];
  const float* bho = (const float*)d_in[18];
  float* out = (float*)d_out;

  char* ws = (char*)d_ws;
  // fast layout (same offsets as r2-r13; Wpk uses 16 MB of its 32 MB slot)
  unsigned short* Wpk   = (unsigned short*)ws;                 // 16 MB
  float*          biasC = (float*)(ws + 33554432);             // 16 KB
  int*            cnt   = (int*)(ws + 33570816);               // 64 KB slot (uses 576 B)
  unsigned short* hseq  = (unsigned short*)(ws + 33636352);    // 513*131072
  unsigned short* xb    = (unsigned short*)(ws + 100876288);   // 64 MB
  const size_t need_fast_xb = 100876288ull + 67108864ull;      // 167985152

  // legacy layout
  unsigned short* Wl_  = (unsigned short*)ws;                  // 32 MB hi+lo
  unsigned short* hb   = (unsigned short*)(ws + 33570816);     // 256 KB

  if (ws_size >= need_fast_xb) {
    pack_w_single<<<4096, 256, 0, stream>>>(wii, whi, wif, whf, wig, whg, wio, who, Wpk);
    pack_bias<<<16, 256, 0, stream>>>(bii, bhi, bif, bhf, big, bhg, bio, bho, biasC);
    conv_x<<<32768, 256, 0, stream>>>(xin, xb);
    hipMemsetAsync(cnt, 0, 4096, stream);

    void* ka[] = {(void*)&Wpk, (void*)&biasC, (void*)&xb,
                  (void*)&hseq, (void*)&cnt, (void*)&h0, (void*)&c0, (void*)&out};
    hipLaunchCooperativeKernel(reinterpret_cast<const void*>(&lstm_fast12),
                               dim3(256), dim3(1024), ka, 0, stream);
    conv_out<<<32768, 256, 0, stream>>>(hseq, out);
  } else {
    pack_w<<<8192, 256, 0, stream>>>(wii, whi, wif, whf, wig, whg, wio, who,
                                     Wl_, Wl_ + 8388608);
    pack_bias<<<16, 256, 0, stream>>>(bii, bhi, bif, bhf, big, bhg, bio, bho, biasC);
    void* ka[] = {(void*)&Wl_, (void*)&biasC, (void*)&xin,
                  (void*)&hb, (void*)&h0, (void*)&c0, (void*)&out};
    hipLaunchCooperativeKernel(reinterpret_cast<const void*>(&lstm_seq_legacy),
                               dim3(256), dim3(512), ka, 0, stream);
  }
}

// Round 15
// 3437.985 us; speedup vs baseline: 1.3503x; 1.2674x over previous
//
#include <hip/hip_runtime.h>
#include <hip/hip_bf16.h>
#include <hip/hip_cooperative_groups.h>

namespace cg = cooperative_groups;

using s16x8 = __attribute__((ext_vector_type(8))) short;   // 8 bf16 (4 VGPRs) MFMA frag
using f32x4 = __attribute__((ext_vector_type(4))) float;   // MFMA accumulator

constexpr int BB = 64;    // batch
constexpr int SS = 512;   // seq len
constexpr int II = 1024;  // input dim
constexpr int HH = 1024;  // hidden dim

__device__ __forceinline__ unsigned short f2bf(float f) {
  unsigned u = __float_as_uint(f);
  unsigned r = u + 0x7fffu + ((u >> 16) & 1u);   // RN-even
  return (unsigned short)(r >> 16);
}
__device__ __forceinline__ float bf2f(unsigned short h) {
  return __uint_as_float(((unsigned)h) << 16);
}

// ---------------------------------------------------------------------------
// Single bf16 W in MFMA-linear fragment order (16 MB):
// Wpk[blk 256][ks 2][kb 32][lane 64][e 8]; lane: n=lane&15 (gate-row), u=lane>>4;
// element k (within ks-part) = kb*32 + u*8 + e.
// ---------------------------------------------------------------------------
__global__ void __launch_bounds__(256) pack_w_single(
    const float* __restrict__ wii, const float* __restrict__ whi_,
    const float* __restrict__ wif, const float* __restrict__ whf,
    const float* __restrict__ wig, const float* __restrict__ whg,
    const float* __restrict__ wio, const float* __restrict__ who,
    unsigned short* __restrict__ Wpk)
{
  unsigned f = blockIdx.x * 256 + threadIdx.x;   // frag id, 0..1048575
  int lane = f & 63;
  int kb   = (f >> 6) & 31;
  int ks   = (f >> 11) & 1;
  int blk  = (int)(f >> 12);
  int n = lane & 15, u = lane >> 4;
  int hc = blk * 4 + (n >> 2), g = n & 3;
  int k  = kb * 32 + u * 8;
  const float* wi4[4] = {wii, wif, wig, wio};
  const float* wh4[4] = {whi_, whf, whg, who};
  const float* src = (ks == 0) ? (wi4[g] + (size_t)hc * 1024 + k)
                               : (wh4[g] + (size_t)hc * 1024 + k);
  float4 v0 = *(const float4*)src;
  float4 v1 = *(const float4*)(src + 4);
  s16x8 r;
  r[0] = (short)f2bf(v0.x); r[1] = (short)f2bf(v0.y);
  r[2] = (short)f2bf(v0.z); r[3] = (short)f2bf(v0.w);
  r[4] = (short)f2bf(v1.x); r[5] = (short)f2bf(v1.y);
  r[6] = (short)f2bf(v1.z); r[7] = (short)f2bf(v1.w);
  *(s16x8*)(Wpk + (size_t)f * 8) = r;
}

__global__ void __launch_bounds__(256) pack_bias(
    const float* __restrict__ bii, const float* __restrict__ bhi,
    const float* __restrict__ bif, const float* __restrict__ bhf,
    const float* __restrict__ big, const float* __restrict__ bhg,
    const float* __restrict__ bio, const float* __restrict__ bho,
    float* __restrict__ biasC)
{
  int cidx = blockIdx.x * 256 + threadIdx.x;  // 0..4095
  int col = cidx & 15, blk = cidx >> 4;
  int hc = blk * 4 + (col >> 2), g = col & 3;
  const float* bi4[4] = {bii, bif, big, bio};
  const float* bh4[4] = {bhi, bhf, bhg, bho};
  biasC[cidx] = bi4[g][hc] + bh4[g][hc];
}

// x [B][S][I] fp32 -> xb [S][B][I] bf16
__global__ void __launch_bounds__(256) conv_x(const float* __restrict__ x,
                                              unsigned short* __restrict__ xb)
{
  int bs = blockIdx.x;
  int b = bs >> 9, s = bs & 511;
  float4 v = *(const float4*)(x + ((size_t)b * 512 + s) * 1024 + threadIdx.x * 4);
  *(ushort4*)(xb + ((size_t)s * 64 + b) * 1024 + threadIdx.x * 4) =
      make_ushort4(f2bf(v.x), f2bf(v.y), f2bf(v.z), f2bf(v.w));
}

// ---------------------------------------------------------------------------
// hseq BLOCK-MAJOR layout [S+1][blk 256][b 64][4] bf16 -> out [B][S][H] fp32.
// LDS transpose: coalesced reads (linear hseq) AND coalesced writes (h-major).
// grid 2048: bid = t*4 + q (q = column quarter of 256 cols).
// ---------------------------------------------------------------------------
__global__ void __launch_bounds__(256) conv_out_t(const unsigned short* __restrict__ hseq,
                                                  float* __restrict__ out)
{
  __shared__ float tile[64][257];  // [b][c within quarter], 257 stride: conflict-free
  int bid = blockIdx.x;
  int t = bid >> 2, q = bid & 3;
  const unsigned short* src = hseq + (size_t)(t + 1) * 65536 + q * 16384;
#pragma unroll
  for (int it = 0; it < 16; ++it) {
    int idx = it * 256 + threadIdx.x;   // ushort4 units; 64 per blkg (consec = consec b)
    int blkg = idx >> 6;                // 0..63 within quarter
    int b = idx & 63;
    ushort4 v = *(const ushort4*)(src + idx * 4);
    int c = blkg * 4;
    tile[b][c + 0] = bf2f(v.x); tile[b][c + 1] = bf2f(v.y);
    tile[b][c + 2] = bf2f(v.z); tile[b][c + 3] = bf2f(v.w);
  }
  __syncthreads();
#pragma unroll
  for (int it = 0; it < 16; ++it) {
    int idx = it * 256 + threadIdx.x;   // float4 units; 64 per b row
    int b = idx >> 6;
    int c4 = idx & 63;
    float4 o = *(const float4*)&tile[b][c4 * 4];
    *(float4*)(out + ((size_t)b * 512 + t) * 1024 + q * 256 + c4 * 4) = o;
  }
}

// ---------------------------------------------------------------------------
// Hierarchical monotone barrier (r4; probe-measured inside 2.45us skeleton).
// ---------------------------------------------------------------------------
__device__ __forceinline__ void hbar_arrive(int* cnt, int blk, int kbar) {
  int g = blk & 7;
  int* lp = cnt + g * 16;
  __hip_atomic_fetch_add(lp, 1, __ATOMIC_RELAXED, __HIP_MEMORY_SCOPE_AGENT);
  if (blk < 8) {   // master of group g == blk
    while (__hip_atomic_load(lp, __ATOMIC_RELAXED, __HIP_MEMORY_SCOPE_AGENT) < 32 * kbar)
      __builtin_amdgcn_s_sleep(1);
    __hip_atomic_fetch_add(cnt + 8 * 16, 1, __ATOMIC_RELAXED, __HIP_MEMORY_SCOPE_AGENT);
  }
}
__device__ __forceinline__ void hbar_spin(int* cnt, int kbar) {
  int* gp = cnt + 8 * 16;
  while (__hip_atomic_load(gp, __ATOMIC_RELAXED, __HIP_MEMORY_SCOPE_AGENT) < 8 * kbar)
    __builtin_amdgcn_s_sleep(1);
}

// K-quarter x-GEMM (xb layout [S][B][I], 8x b128 loads) -- unchanged from r14
__device__ __forceinline__ void gemm_q(const unsigned short* __restrict__ aptr,
                                       const s16x8* __restrict__ WlV, int wb,
                                       f32x4& out) {
  s16x8 a[8];
#pragma unroll
  for (int kb = 0; kb < 8; ++kb) a[kb] = *(const s16x8*)(aptr + kb * 32);
  f32x4 c0_ = {0.f, 0.f, 0.f, 0.f}, c1_ = c0_;
#pragma unroll
  for (int kb = 0; kb < 8; kb += 2) {
    c0_ = __builtin_amdgcn_mfma_f32_16x16x32_bf16(a[kb],     WlV[wb + kb * 64],       c0_, 0, 0, 0);
    c1_ = __builtin_amdgcn_mfma_f32_16x16x32_bf16(a[kb + 1], WlV[wb + (kb + 1) * 64], c1_, 0, 0, 0);
  }
  out = c0_ + c1_;
}

// K-quarter h-GEMM for BLOCK-MAJOR hseq: frag kb covers cols kq*256+kb*32+u*8+e,
// i.e. blkg = kq*64+kb*8+u*2 (+1 for e>=4). Two 8B lane-coalesced loads per frag.
__device__ __forceinline__ void gemm_qh(const unsigned short* __restrict__ p0,
                                        const s16x8* __restrict__ WlV, int wb,
                                        f32x4& out) {
  s16x8 a[8];
#pragma unroll
  for (int kb = 0; kb < 8; ++kb) {
    ushort4 lo = *(const ushort4*)(p0 + kb * 2048);          // blkg even half
    ushort4 hi = *(const ushort4*)(p0 + kb * 2048 + 256);    // blkg odd half
    s16x8 v;
    v[0] = (short)lo.x; v[1] = (short)lo.y; v[2] = (short)lo.z; v[3] = (short)lo.w;
    v[4] = (short)hi.x; v[5] = (short)hi.y; v[6] = (short)hi.z; v[7] = (short)hi.w;
    a[kb] = v;
  }
  f32x4 c0_ = {0.f, 0.f, 0.f, 0.f}, c1_ = c0_;
#pragma unroll
  for (int kb = 0; kb < 8; kb += 2) {
    c0_ = __builtin_amdgcn_mfma_f32_16x16x32_bf16(a[kb],     WlV[wb + kb * 64],       c0_, 0, 0, 0);
    c1_ = __builtin_amdgcn_mfma_f32_16x16x32_bf16(a[kb + 1], WlV[wb + (kb + 1) * 64], c1_, 0, 0, 0);
  }
  out = c0_ + c1_;
}

// ---------------------------------------------------------------------------
// Persistent LSTM v14 = r14 (16 waves, K-quarter) + FULL-LINE h-flush:
// hseq block-major [S+1][blk][b][4]; each block's flush = one contiguous
// 512B span (8 full 64B lines, no cross-XCD partial-line RMW).
// ---------------------------------------------------------------------------
__global__ void __launch_bounds__(1024, 1) lstm_fast13(
    const unsigned short* __restrict__ Wpk,  // [256][2][32][64][8] bf16 (16 MB)
    const float* __restrict__ biasC,         // [256][16]
    const unsigned short* __restrict__ xb,   // [S][B][I] bf16
    unsigned short* __restrict__ hseq,       // [S+1][blk][b][4] bf16 rotating
    int* __restrict__ cnt,                   // 9 lines x 64B, monotone
    const float* __restrict__ h0,
    const float* __restrict__ c0,
    float* __restrict__ out)                 // [hidden_seq][h_f][c_f]
{
  __shared__ s16x8 WlV[4096];                // 64 KB single-W frags
  __shared__ float gX[4][64][17];            // x partials per K-quarter
  __shared__ float gH[4][64][17];            // h partials per K-quarter
  __shared__ float biasLds[16];
  __shared__ short hOutLds[64][4];           // staged h_{t+1} for 8B flush

  const int tid  = threadIdx.x;
  const int blk  = blockIdx.x;
  const int wave = tid >> 6, lane = tid & 63;
  const int m  = wave & 3;        // batch tile
  const int kq = wave >> 2;       // K-quarter (0..3)
  const int arow = m * 16 + (lane & 15);
  const int u    = lane >> 4;
  const int koff = u * 8;
  const int aoff = arow * 1024 + kq * 256 + koff;     // x offset in a t-slot
  const int hoff = (kq * 64 + u * 2) * 256 + arow * 4; // h offset (block-major)
  const int wxb = (kq * 8) * 64 + lane;               // x-part W frag base in LDS
  const int whb = (32 + kq * 8) * 64 + lane;          // h-part W frag base in LDS
  const int drow = m * 16 + u * 4;
  const int dcol = lane & 15;

  // stage this block's W chunk (64 KB linear; frag order == read order)
  {
    const s16x8* src = (const s16x8*)(Wpk + (size_t)blk * 32768);
#pragma unroll
    for (int it = 0; it < 4; ++it) WlV[it * 1024 + tid] = src[it * 1024 + tid];
  }
  if (tid < 16) biasLds[tid] = biasC[blk * 16 + tid];

  // init hseq slot 0 (block-major: each block writes ITS OWN 512B span)
  if (tid < 64) {
    float4 v = *(const float4*)(h0 + (size_t)tid * 1024 + blk * 4);
    unsigned lo = (unsigned)f2bf(v.x) | ((unsigned)f2bf(v.y) << 16);
    unsigned hi = (unsigned)f2bf(v.z) | ((unsigned)f2bf(v.w) << 16);
    unsigned long long w = (unsigned long long)lo | ((unsigned long long)hi << 32);
    __hip_atomic_store((unsigned long long*)(hseq + blk * 256 + tid * 4),
                       w, __ATOMIC_RELAXED, __HIP_MEMORY_SCOPE_AGENT);
  }
  const int rb_batch = tid >> 2, rb_j = tid & 3;
  float c_reg = 0.f;
  if (tid < 256) c_reg = c0[rb_batch * 1024 + blk * 4 + rb_j];

  __syncthreads();                           // W staged; h0 stores drained

  // prologue: x-GEMM(0) on all 16 waves (K-quartered)
  f32x4 xacc;
  gemm_q(xb + aoff, WlV, wxb, xacc);

  if (tid == 256) { hbar_arrive(cnt, blk, 1); hbar_spin(cnt, 1); }
  __syncthreads();                           // hseq slot 0 globally visible

  for (int t = 0; t < SS; ++t) {
    // ---- phase A: publish xacc(t); h-GEMM(t) from block-major hseq ----
#pragma unroll
    for (int r = 0; r < 4; ++r) gX[kq][drow + r][dcol] = xacc[r];
    {
      f32x4 hs;
      gemm_qh(hseq + (size_t)t * 65536 + hoff, WlV, whb, hs);
#pragma unroll
      for (int r = 0; r < 4; ++r) gH[kq][drow + r][dcol] = hs[r];
    }
    __syncthreads();                         // S1

    // ---- phase B: gate math over 8 partials ----
    if (tid < 256) {
      int c0i = rb_j * 4;
      float si = (gX[0][rb_batch][c0i + 0] + gX[1][rb_batch][c0i + 0])
               + (gX[2][rb_batch][c0i + 0] + gX[3][rb_batch][c0i + 0])
               + (gH[0][rb_batch][c0i + 0] + gH[1][rb_batch][c0i + 0])
               + (gH[2][rb_batch][c0i + 0] + gH[3][rb_batch][c0i + 0]) + biasLds[c0i + 0];
      float sf = (gX[0][rb_batch][c0i + 1] + gX[1][rb_batch][c0i + 1])
               + (gX[2][rb_batch][c0i + 1] + gX[3][rb_batch][c0i + 1])
               + (gH[0][rb_batch][c0i + 1] + gH[1][rb_batch][c0i + 1])
               + (gH[2][rb_batch][c0i + 1] + gH[3][rb_batch][c0i + 1]) + biasLds[c0i + 1];
      float sg = (gX[0][rb_batch][c0i + 2] + gX[1][rb_batch][c0i + 2])
               + (gX[2][rb_batch][c0i + 2] + gX[3][rb_batch][c0i + 2])
               + (gH[0][rb_batch][c0i + 2] + gH[1][rb_batch][c0i + 2])
               + (gH[2][rb_batch][c0i + 2] + gH[3][rb_batch][c0i + 2]) + biasLds[c0i + 2];
      float so = (gX[0][rb_batch][c0i + 3] + gX[1][rb_batch][c0i + 3])
               + (gX[2][rb_batch][c0i + 3] + gX[3][rb_batch][c0i + 3])
               + (gH[0][rb_batch][c0i + 3] + gH[1][rb_batch][c0i + 3])
               + (gH[2][rb_batch][c0i + 3] + gH[3][rb_batch][c0i + 3]) + biasLds[c0i + 3];
      float iv = 1.f / (1.f + __expf(-si));
      float fv = 1.f / (1.f + __expf(-sf));
      float gv = tanhf(sg);
      float ov = 1.f / (1.f + __expf(-so));
      c_reg = fv * c_reg + iv * gv;
      float hv = ov * tanhf(c_reg);
      hOutLds[rb_batch][rb_j] = (short)f2bf(hv);
      if (t == SS - 1) {
        int hcg = blk * 4 + rb_j;
        out[(size_t)BB * SS * HH + rb_batch * 1024 + hcg] = hv;            // h_f fp32
        out[(size_t)BB * SS * HH + 65536 + rb_batch * 1024 + hcg] = c_reg; // c_f fp32
      }
    }
    __syncthreads();                         // S2

    // ---- phase C: FULL-LINE flush: one contiguous 512B span per block ----
    if (tid < 64) {
      unsigned long long v = *(const unsigned long long*)&hOutLds[tid][0];
      __hip_atomic_store(
          (unsigned long long*)(hseq + (size_t)(t + 1) * 65536 + blk * 256 + tid * 4),
          v, __ATOMIC_RELAXED, __HIP_MEMORY_SCOPE_AGENT);
    }
    __syncthreads();                         // S3: flush drained per thread

    // ---- phase D: arrive; x-GEMM(t+1) under the wait; spin ----
    if (t + 1 < SS) {
      if (tid == 256) hbar_arrive(cnt, blk, t + 2);
      gemm_q(xb + (size_t)(t + 1) * 65536 + aoff, WlV, wxb, xacc);
      if (tid == 256) hbar_spin(cnt, t + 2);
      __syncthreads();                       // S4: h_{t+1} globally visible
    }
  }
}

// ---------------------------------------------------------------------------
// LEGACY fallback (cg::grid.sync) for small ws_size. Unchanged.
// ---------------------------------------------------------------------------
__global__ void __launch_bounds__(256) pack_w(
    const float* __restrict__ wii, const float* __restrict__ whi_,
    const float* __restrict__ wif, const float* __restrict__ whf,
    const float* __restrict__ wig, const float* __restrict__ whg,
    const float* __restrict__ wio, const float* __restrict__ who,
    unsigned short* __restrict__ Whi, unsigned short* __restrict__ Wlo)
{
  size_t idx = ((size_t)blockIdx.x * 256 + threadIdx.x) * 4;
  int k   = (int)(idx & 2047);
  int rg  = (int)(idx >> 11);
  int row = rg & 15;
  int blk = rg >> 4;
  int hc  = blk * 4 + (row >> 2);
  int g   = row & 3;
  const float* wi4[4] = {wii, wif, wig, wio};
  const float* wh4[4] = {whi_, whf, whg, who};
  const float* src = (k < 1024) ? (wi4[g] + (size_t)hc * 1024 + k)
                                : (wh4[g] + (size_t)hc * 1024 + (k - 1024));
  float4 v = *(const float4*)src;
  float vv[4] = {v.x, v.y, v.z, v.w};
  unsigned short h_[4], l_[4];
#pragma unroll
  for (int j = 0; j < 4; ++j) {
    unsigned short h = f2bf(vv[j]);
    h_[j] = h;
    l_[j] = f2bf(vv[j] - bf2f(h));
  }
  *(ushort4*)(Whi + idx) = make_ushort4(h_[0], h_[1], h_[2], h_[3]);
  *(ushort4*)(Wlo + idx) = make_ushort4(l_[0], l_[1], l_[2], l_[3]);
}

__global__ void __launch_bounds__(512, 1) lstm_seq_legacy(
    const unsigned short* __restrict__ W,
    const float* __restrict__ biasC,
    const float* __restrict__ xin,
    unsigned short* __restrict__ hb,
    const float* __restrict__ h0,
    const float* __restrict__ c0,
    float* __restrict__ out)
{
  __shared__ short Wl[2][16][2048];
  __shared__ float gLds[2][64][17];
  __shared__ float biasLds[16];

  const int tid  = threadIdx.x;
  const int blk  = blockIdx.x;
  const int wave = tid >> 6;
  const int lane = tid & 63;
  const int m    = wave >> 1;
  const int ks   = wave & 1;
  const int arow = m * 16 + (lane & 15);
  const int koff = (lane >> 4) * 8;
  const int brow = lane & 15;
  const int bswz = (brow & 7) << 4;

  {
    const char* srcH = (const char*)W + (size_t)blk * 65536;
    const char* srcL = (const char*)W + 16777216u + (size_t)blk * 65536;
    char* dstH = (char*)&Wl[0][0][0];
    char* dstL = (char*)&Wl[1][0][0];
#pragma unroll
    for (int it = 0; it < 8; ++it) {
      int boff = it * 8192 + tid * 16;
      int row  = boff >> 12;
      int colb = boff & 4095;
      int dsw  = row * 4096 + (colb ^ ((row & 7) << 4));
      *(int4*)(dstH + dsw) = *(const int4*)(srcH + boff);
      *(int4*)(dstL + dsw) = *(const int4*)(srcL + boff);
    }
  }
  if (tid < 16) biasLds[tid] = biasC[blk * 16 + tid];
  if (tid < 256) {
    int e = blk * 256 + tid;
    hb[e] = f2bf(h0[e]);
  }
  const int rb_batch = tid >> 2, rb_j = tid & 3;
  float c_reg = 0.f;
  if (tid < 256) c_reg = c0[rb_batch * 1024 + blk * 4 + rb_j];

  cg::grid_group grid = cg::this_grid();
  __syncthreads();
  grid.sync();

  const char* wrow = (const char*)&Wl[0][0][0] + brow * 4096;
  const int kbyte = ks * 2048;

  for (int t = 0; t < SS; ++t) {
    const unsigned short* hcur = hb + (t & 1) * 65536;
    f32x4 accH = {0.f, 0.f, 0.f, 0.f};
    f32x4 accL = {0.f, 0.f, 0.f, 0.f};

    if (ks == 1) {
      const unsigned short* aptr = hcur + arow * 1024 + koff;
#pragma unroll
      for (int kk = 0; kk < 1024; kk += 32) {
        s16x8 a = *(const s16x8*)(aptr + kk);
        int cb = (kbyte + (kk + koff) * 2) ^ bswz;
        s16x8 bh = *(const s16x8*)(wrow + cb);
        s16x8 bl = *(const s16x8*)(wrow + 65536 + cb);
        accH = __builtin_amdgcn_mfma_f32_16x16x32_bf16(a, bh, accH, 0, 0, 0);
        accL = __builtin_amdgcn_mfma_f32_16x16x32_bf16(a, bl, accL, 0, 0, 0);
      }
    } else {
      const float* xp = xin + ((size_t)arow * 512 + t) * 1024 + koff;
#pragma unroll
      for (int kk = 0; kk < 1024; kk += 32) {
        float4 f0 = *(const float4*)(xp + kk);
        float4 f1 = *(const float4*)(xp + kk + 4);
        s16x8 a;
        a[0] = (short)f2bf(f0.x); a[1] = (short)f2bf(f0.y);
        a[2] = (short)f2bf(f0.z); a[3] = (short)f2bf(f0.w);
        a[4] = (short)f2bf(f1.x); a[5] = (short)f2bf(f1.y);
        a[6] = (short)f2bf(f1.z); a[7] = (short)f2bf(f1.w);
        int cb = ((kk + koff) * 2) ^ bswz;
        s16x8 bh = *(const s16x8*)(wrow + cb);
        s16x8 bl = *(const s16x8*)(wrow + 65536 + cb);
        accH = __builtin_amdgcn_mfma_f32_16x16x32_bf16(a, bh, accH, 0, 0, 0);
        accL = __builtin_amdgcn_mfma_f32_16x16x32_bf16(a, bl, accL, 0, 0, 0);
      }
    }

    {
      f32x4 acc = accH + accL;
      int drow = m * 16 + (lane >> 4) * 4;
      int dcol = lane & 15;
#pragma unroll
      for (int r = 0; r < 4; ++r) gLds[ks][drow + r][dcol] = acc[r];
    }
    __syncthreads();

    if (tid < 256) {
      int c0i = rb_j * 4;
      float si = gLds[0][rb_batch][c0i + 0] + gLds[1][rb_batch][c0i + 0] + biasLds[c0i + 0];
      float sf = gLds[0][rb_batch][c0i + 1] + gLds[1][rb_batch][c0i + 1] + biasLds[c0i + 1];
      float sg = gLds[0][rb_batch][c0i + 2] + gLds[1][rb_batch][c0i + 2] + biasLds[c0i + 2];
      float so = gLds[0][rb_batch][c0i + 3] + gLds[1][rb_batch][c0i + 3] + biasLds[c0i + 3];
      float iv = 1.f / (1.f + __expf(-si));
      float fv = 1.f / (1.f + __expf(-sf));
      float gv = tanhf(sg);
      float ov = 1.f / (1.f + __expf(-so));
      c_reg = fv * c_reg + iv * gv;
      float hv = ov * tanhf(c_reg);
      int hcg = blk * 4 + rb_j;
      out[(size_t)rb_batch * (SS * HH) + (size_t)t * HH + hcg] = hv;
      hb[((t + 1) & 1) * 65536 + rb_batch * 1024 + hcg] = f2bf(hv);
      if (t == SS - 1) {
        out[(size_t)BB * SS * HH + rb_batch * 1024 + hcg] = hv;
        out[(size_t)BB * SS * HH + 65536 + rb_batch * 1024 + hcg] = c_reg;
      }
    }
    grid.sync();
  }
}

extern "C" void kernel_launch(void* const* d_in, const int* in_sizes, int n_in,
                              void* d_out, int out_size, void* d_ws, size_t ws_size,
                              hipStream_t stream) {
  const float* xin = (const float*)d_in[0];
  const float* h0  = (const float*)d_in[1];
  const float* c0  = (const float*)d_in[2];
  const float* wii = (const float*)d_in[3];
  const float* whi = (const float*)d_in[4];
  const float* bii = (const float*)d_in[5];
  const float* bhi = (const float*)d_in[6];
  const float* wif = (const float*)d_in[7];
  const float* whf = (const float*)d_in[8];
  const float* bif = (const float*)d_in[9];
  const float* bhf = (const float*)d_in[10];
  const float* wig = (const float*)d_in[11];
  const float* whg = (const float*)d_in[12];
  const float* big = (const float*)d_in[13];
  const float* bhg = (const float*)d_in[14];
  const float* wio = (const float*)d_in[15];
  const float* who = (const float*)d_in[16];
  const float* bio = (const float*)d_in[17];
  const float* bho = (const float*)d_in[18];
  float* out = (float*)d_out;

  char* ws = (char*)d_ws;
  // fast layout (same offsets as r2-r14; Wpk uses 16 MB of its 32 MB slot)
  unsigned short* Wpk   = (unsigned short*)ws;                 // 16 MB
  float*          biasC = (float*)(ws + 33554432);             // 16 KB
  int*            cnt   = (int*)(ws + 33570816);               // 64 KB slot (uses 576 B)
  unsigned short* hseq  = (unsigned short*)(ws + 33636352);    // 513*131072 (block-major)
  unsigned short* xb    = (unsigned short*)(ws + 100876288);   // 64 MB
  const size_t need_fast_xb = 100876288ull + 67108864ull;      // 167985152

  // legacy layout
  unsigned short* Wl_  = (unsigned short*)ws;                  // 32 MB hi+lo
  unsigned short* hb   = (unsigned short*)(ws + 33570816);     // 256 KB

  if (ws_size >= need_fast_xb) {
    pack_w_single<<<4096, 256, 0, stream>>>(wii, whi, wif, whf, wig, whg, wio, who, Wpk);
    pack_bias<<<16, 256, 0, stream>>>(bii, bhi, bif, bhf, big, bhg, bio, bho, biasC);
    conv_x<<<32768, 256, 0, stream>>>(xin, xb);
    hipMemsetAsync(cnt, 0, 4096, stream);

    void* ka[] = {(void*)&Wpk, (void*)&biasC, (void*)&xb,
                  (void*)&hseq, (void*)&cnt, (void*)&h0, (void*)&c0, (void*)&out};
    hipLaunchCooperativeKernel(reinterpret_cast<const void*>(&lstm_fast13),
                               dim3(256), dim3(1024), ka, 0, stream);
    conv_out_t<<<2048, 256, 0, stream>>>(hseq, out);
  } else {
    pack_w<<<8192, 256, 0, stream>>>(wii, whi, wif, whf, wig, whg, wio, who,
                                     Wl_, Wl_ + 8388608);
    pack_bias<<<16, 256, 0, stream>>>(bii, bhi, bif, bhf, big, bhg, bio, bho, biasC);
    void* ka[] = {(void*)&Wl_, (void*)&biasC, (void*)&xin,
                  (void*)&hb, (void*)&h0, (void*)&c0, (void*)&out};
    hipLaunchCooperativeKernel(reinterpret_cast<const void*>(&lstm_seq_legacy),
                               dim3(256), dim3(512), ka, 0, stream);
  }
}